// Round 2
// 458.253 us; speedup vs baseline: 1.0830x; 1.0830x over previous
//
#include <hip/hip_runtime.h>
#include <math.h>

namespace {
constexpr int B_  = 64;
constexpr int T_  = 1380;
constexpr int XD_ = 96;
constexpr int HD_ = 192;
constexpr int CN_ = 345;
constexpr int CP_ = 384;                       // padded CN
constexpr int TP_ = 1392;                      // padded T for Hth rows
constexpr int TP2_ = 1408;                     // padded T for k12 K-dim (22*64)
constexpr int TH_ = 690;                       // T/2 (u-split in k3)
constexpr float SCALE_ = 0.00736569563735987f; // 1/sqrt(96*192)
}

typedef __attribute__((ext_vector_type(8))) short bf16x8;
typedef __attribute__((ext_vector_type(4))) float f32x4;
typedef unsigned short u16;
typedef unsigned int   u32;

__device__ __forceinline__ u16 f2bf(float f) {
    union { float f; u32 u; } c; c.f = f;
    u32 r = (c.u + 0x7fffu + ((c.u >> 16) & 1u)) >> 16;
    return (u16)r;
}
__device__ __forceinline__ float bf2f(u16 s) {
    union { u32 u; float f; } c; c.u = ((u32)s) << 16;
    return c.f;
}

// ---------------------------------------------------------------------------
// K0h: fused H prep — one read of H produces Hh/Hl ([b][u][h] bf16 hi/lo)
// and Hth ([b][h][u] bf16 hi, row stride TP_).  grid (22, 3, B).
// ---------------------------------------------------------------------------
__global__ __launch_bounds__(256) void k0_h(const float* __restrict__ Hg,
                                            u16* __restrict__ Hh,
                                            u16* __restrict__ Hl,
                                            u16* __restrict__ Hth) {
    __shared__ u16 til[64][68];
    const int tid = threadIdx.x;
    const int u0 = blockIdx.x * 64, h0 = blockIdx.y * 64, b = blockIdx.z;
#pragma unroll
    for (int i = 0; i < 8; i++) {
        int lin = i * 256 + tid;           // 0..2047
        int r = lin >> 5;                  // u row 0..63
        int cp = lin & 31;                 // float2 col
        int u = u0 + r, h = h0 + cp * 2;
        float2 v = make_float2(0.f, 0.f);
        if (u < T_) v = *(const float2*)(Hg + ((size_t)b * T_ + u) * HD_ + h);
        u16 hx = f2bf(v.x), hy = f2bf(v.y);
        u16 lx = f2bf(v.x - bf2f(hx)), ly = f2bf(v.y - bf2f(hy));
        if (u < T_) {
            *(u32*)(Hh + ((size_t)b * T_ + u) * HD_ + h) = (u32)hx | ((u32)hy << 16);
            *(u32*)(Hl + ((size_t)b * T_ + u) * HD_ + h) = (u32)lx | ((u32)ly << 16);
        }
        til[cp * 2][r]     = hx;
        til[cp * 2 + 1][r] = hy;
    }
    __syncthreads();
#pragma unroll
    for (int i = 0; i < 4; i++) {
        int lin = i * 256 + tid;
        int hh = lin >> 4, cc = lin & 15;
        int u = u0 + cc * 4;
        if (u + 4 <= T_) {
            ushort4 v;
            v.x = til[hh][cc * 4 + 0];
            v.y = til[hh][cc * 4 + 1];
            v.z = til[hh][cc * 4 + 2];
            v.w = til[hh][cc * 4 + 3];
            *(ushort4*)(Hth + ((size_t)b * HD_ + h0 + hh) * TP_ + u) = v;
        }
    }
}

// ---------------------------------------------------------------------------
// K0c: X -> Xth/Xtl [b][x][t] bf16 hi/lo, t padded to TP2_ with zeros.
// ---------------------------------------------------------------------------
__global__ __launch_bounds__(256) void k0_x(const float* __restrict__ Xg,
                                            u16* __restrict__ Xth,
                                            u16* __restrict__ Xtl) {
    __shared__ __align__(16) u16 tih[96][72];
    __shared__ __align__(16) u16 til[96][72];
    const int tid = threadIdx.x;
    const int t0 = blockIdx.x * 64, b = blockIdx.y;
#pragma unroll
    for (int i = 0; i < 24; i++) {
        int lin = i * 256 + tid;
        int r = lin / 96, x = lin % 96;
        float v = (t0 + r < T_) ? Xg[((size_t)b * T_ + t0 + r) * XD_ + x] : 0.f;
        u16 hi = f2bf(v);
        tih[x][r] = hi;
        til[x][r] = f2bf(v - bf2f(hi));
    }
    __syncthreads();
#pragma unroll
    for (int i = 0; i < 6; i++) {
        int id = i * 256 + tid;
        int buf = (id >= 768);
        int cid = buf ? id - 768 : id;
        int x = cid >> 3, col = cid & 7;
        uint4 v = *(const uint4*)&(buf ? til : tih)[x][col * 8];
        u16* dst = (buf ? Xtl : Xth) + ((size_t)b * XD_ + x) * TP2_ + t0 + col * 8;
        *(uint4*)dst = v;
    }
}

// ---------------------------------------------------------------------------
// K0d: W2 -> W2h/W2l [CP_][TP2_] bf16 hi/lo, zero padded both dims.
// ---------------------------------------------------------------------------
__global__ __launch_bounds__(256) void k0_w2(const float* __restrict__ W2g,
                                             u16* __restrict__ W2h,
                                             u16* __restrict__ W2l) {
    const int n = CP_ * (TP2_ / 2);
    for (int i = blockIdx.x * 256 + threadIdx.x; i < n; i += gridDim.x * 256) {
        int c = i / (TP2_ / 2), tc = i % (TP2_ / 2);
        int t = tc * 2;
        float v0 = 0.f, v1 = 0.f;
        if (c < CN_) {
            if (t < T_)     v0 = W2g[(size_t)c * T_ + t];
            if (t + 1 < T_) v1 = W2g[(size_t)c * T_ + t + 1];
        }
        u16 h0 = f2bf(v0), h1 = f2bf(v1);
        u16 l0 = f2bf(v0 - bf2f(h0)), l1 = f2bf(v1 - bf2f(h1));
        ((u32*)W2h)[i] = (u32)h0 | ((u32)h1 << 16);
        ((u32*)W2l)[i] = (u32)l0 | ((u32)l1 << 16);
    }
}

// ---------------------------------------------------------------------------
// K0e: W1 [x][h] -> W1th/W1tl [h][x] bf16 hi/lo (tiny).
// ---------------------------------------------------------------------------
__global__ __launch_bounds__(256) void k0_w1(const float* __restrict__ W1g,
                                             u16* __restrict__ W1th,
                                             u16* __restrict__ W1tl) {
    int i = blockIdx.x * 256 + threadIdx.x;
    if (i < HD_ * XD_) {
        int h = i / XD_, x = i % XD_;
        float v = W1g[(size_t)x * HD_ + h];
        u16 hi = f2bf(v);
        W1th[i] = hi;
        W1tl[i] = f2bf(v - bf2f(hi));
    }
}

// ---------------------------------------------------------------------------
// K12: fused MFMA GEMM.  Phase 1: Z[c,x] = W2@X[b] (split-bf16, K=1408).
// Phase 2: Y = SCALE * Z @ W1.
// c-tile 32 -> grid 704 (= 64 b x 11 c-tiles), __launch_bounds__(256,3)
// -> ~3 blocks/CU (was 384 blocks = 1.5/CU, imbalanced, 1-2 waves/SIMD
// -> latency-bound).  XCD swizzle: the 11 c-blocks sharing a b land on
// one XCD so X[b] (1.05 MB) is L2-resident.
// ---------------------------------------------------------------------------
__global__ __launch_bounds__(256, 3) void k12_mfma(const u16* __restrict__ W2h,
                                                   const u16* __restrict__ W2l,
                                                   const u16* __restrict__ Xth,
                                                   const u16* __restrict__ Xtl,
                                                   const u16* __restrict__ W1th,
                                                   const u16* __restrict__ W1tl,
                                                   u16* __restrict__ Ysh,
                                                   u16* __restrict__ Ysl) {
    __shared__ __align__(16) char smem[36864];
    u16* sAh = (u16*)smem;                  // 32 x 72
    u16* sAl = (u16*)(smem + 4608);
    u16* sBh = (u16*)(smem + 9216);         // 96 x 72
    u16* sBl = (u16*)(smem + 23040);
    float* sZ = (float*)smem;               // phase 2: 32 x 100 fp32 (12.8 KB)

    const int tid  = threadIdx.x;
    const int lane = tid & 63;
    const int w    = tid >> 6;
    const int tx   = lane & 15;
    const int quad = lane >> 4;
    const int wc   = w >> 1;              // c-subtile (16 rows)
    const int wx   = w & 1;               // x-half (48 cols)
    // XCD-aware decode: L = xcd + 8*slot; slot -> (b_local, ct)
    const int L    = blockIdx.x;
    const int xcd  = L & 7;
    const int slot = L >> 3;              // 0..87
    const int b    = xcd * 8 + slot / 11;
    const int c0   = (slot % 11) * 32;

    f32x4 accZ[3];
#pragma unroll
    for (int j = 0; j < 3; j++) accZ[j] = (f32x4){0.f, 0.f, 0.f, 0.f};

    uint4 pf[8];
    {
#pragma unroll
        for (int i = 0; i < 2; i++) {
            int id = tid + i * 256;
            int buf = id >> 8, cid = id & 255;
            int row = cid >> 3, col = cid & 7;
            pf[i] = *(const uint4*)((buf ? W2l : W2h) + (size_t)(c0 + row) * TP2_ + col * 8);
        }
#pragma unroll
        for (int i = 0; i < 6; i++) {
            int id = tid + i * 256;
            int buf = (id >= 768) ? 1 : 0;
            int cid = id - buf * 768;
            int row = cid >> 3, col = cid & 7;
            pf[2 + i] = *(const uint4*)((buf ? Xtl : Xth) + ((size_t)b * XD_ + row) * TP2_ + col * 8);
        }
    }

    for (int s = 0; s < 22; s++) {
        __syncthreads();
#pragma unroll
        for (int i = 0; i < 2; i++) {
            int id = tid + i * 256;
            int buf = id >> 8, cid = id & 255;
            int row = cid >> 3, col = cid & 7;
            *(uint4*)((buf ? sAl : sAh) + row * 72 + col * 8) = pf[i];
        }
#pragma unroll
        for (int i = 0; i < 6; i++) {
            int id = tid + i * 256;
            int buf = (id >= 768) ? 1 : 0;
            int cid = id - buf * 768;
            int row = cid >> 3, col = cid & 7;
            *(uint4*)((buf ? sBl : sBh) + row * 72 + col * 8) = pf[2 + i];
        }
        __syncthreads();
        if (s < 21) {
            const int k0 = (s + 1) * 64;
#pragma unroll
            for (int i = 0; i < 2; i++) {
                int id = tid + i * 256;
                int buf = id >> 8, cid = id & 255;
                int row = cid >> 3, col = cid & 7;
                pf[i] = *(const uint4*)((buf ? W2l : W2h) + (size_t)(c0 + row) * TP2_ + k0 + col * 8);
            }
#pragma unroll
            for (int i = 0; i < 6; i++) {
                int id = tid + i * 256;
                int buf = (id >= 768) ? 1 : 0;
                int cid = id - buf * 768;
                int row = cid >> 3, col = cid & 7;
                pf[2 + i] = *(const uint4*)((buf ? Xtl : Xth) + ((size_t)b * XD_ + row) * TP2_ + k0 + col * 8);
            }
        }
        __builtin_amdgcn_s_setprio(1);
#pragma unroll
        for (int sub = 0; sub < 2; sub++) {
            const int kc = sub * 32 + quad * 8;
            bf16x8 ah = *(const bf16x8*)(sAh + (wc * 16 + tx) * 72 + kc);
            bf16x8 al = *(const bf16x8*)(sAl + (wc * 16 + tx) * 72 + kc);
#pragma unroll
            for (int nt = 0; nt < 3; nt++) {
                const int brow = (wx * 3 + nt) * 16 + tx;
                bf16x8 bh = *(const bf16x8*)(sBh + brow * 72 + kc);
                bf16x8 bl = *(const bf16x8*)(sBl + brow * 72 + kc);
                accZ[nt] = __builtin_amdgcn_mfma_f32_16x16x32_bf16(ah, bh, accZ[nt], 0, 0, 0);
                accZ[nt] = __builtin_amdgcn_mfma_f32_16x16x32_bf16(ah, bl, accZ[nt], 0, 0, 0);
                accZ[nt] = __builtin_amdgcn_mfma_f32_16x16x32_bf16(al, bh, accZ[nt], 0, 0, 0);
            }
        }
        __builtin_amdgcn_s_setprio(0);
    }

    __syncthreads();
#pragma unroll
    for (int nt = 0; nt < 3; nt++)
#pragma unroll
        for (int r = 0; r < 4; r++)
            sZ[(wc * 16 + quad * 4 + r) * 100 + (wx * 3 + nt) * 16 + tx] = accZ[nt][r];
    __syncthreads();

    bf16x8 A2h[3], A2l[3];
#pragma unroll
    for (int ks = 0; ks < 3; ks++) {
        const float* zrow = sZ + (wc * 16 + tx) * 100 + ks * 32 + quad * 8;
        bf16x8 vh, vl;
#pragma unroll
        for (int j = 0; j < 8; j++) {
            float v = zrow[j];
            u16 hi = f2bf(v);
            vh[j] = (short)hi;
            vl[j] = (short)f2bf(v - bf2f(hi));
        }
        A2h[ks] = vh; A2l[ks] = vl;
    }

    f32x4 accY[6];
#pragma unroll
    for (int j = 0; j < 6; j++) accY[j] = (f32x4){0.f, 0.f, 0.f, 0.f};
#pragma unroll
    for (int j = 0; j < 6; j++) {
        const int hrow = wx * 96 + j * 16 + tx;
#pragma unroll
        for (int ks = 0; ks < 3; ks++) {
            bf16x8 bh = *(const bf16x8*)(W1th + (size_t)hrow * XD_ + ks * 32 + quad * 8);
            bf16x8 bl = *(const bf16x8*)(W1tl + (size_t)hrow * XD_ + ks * 32 + quad * 8);
            accY[j] = __builtin_amdgcn_mfma_f32_16x16x32_bf16(A2h[ks], bh, accY[j], 0, 0, 0);
            accY[j] = __builtin_amdgcn_mfma_f32_16x16x32_bf16(A2h[ks], bl, accY[j], 0, 0, 0);
            accY[j] = __builtin_amdgcn_mfma_f32_16x16x32_bf16(A2l[ks], bh, accY[j], 0, 0, 0);
        }
    }

#pragma unroll
    for (int r = 0; r < 4; r++) {
        int c = c0 + wc * 16 + quad * 4 + r;
        if (c < CN_) {
            size_t base = ((size_t)b * CN_ + c) * HD_;
#pragma unroll
            for (int j = 0; j < 6; j++) {
                float y = SCALE_ * accY[j][r];
                u16 hi = f2bf(y);
                Ysh[base + wx * 96 + j * 16 + tx] = hi;
                Ysl[base + wx * 96 + j * 16 + tx] = f2bf(y - bf2f(hi));
            }
        }
    }
}

// ---------------------------------------------------------------------------
// K3: MFMA flash attention over a u-half.  1-D grid 512, block 384 = 6 waves.
// Register-prefetch pipeline for the H staging (global latency hides under
// GEMM1/softmax/PV), barrier 3-of-3 dropped (sP rows are written and read
// by the SAME wave -> in-order DS ops suffice), s_setprio(1) around MFMA.
// ---------------------------------------------------------------------------
__global__ __launch_bounds__(384, 2) void k3_mfma(const u16* __restrict__ Ysh,
                                                  const u16* __restrict__ Ysl,
                                                  const u16* __restrict__ Hh,
                                                  const u16* __restrict__ Hl,
                                                  const u16* __restrict__ Hth,
                                                  float* __restrict__ Op,
                                                  float* __restrict__ Ml,
                                                  float* __restrict__ Ll) {
    __shared__ __align__(16) u16 sHh[32][200];
    __shared__ __align__(16) u16 sHl[32][200];
    __shared__ __align__(16) u16 sHt[192][40];
    __shared__ __align__(16) u16 sP[96][40];

    const int tid  = threadIdx.x;
    const int lane = tid & 63;
    const int w    = tid >> 6;            // 0..5
    const int tx   = lane & 15;
    const int quad = lane >> 4;
    // XCD-aware decode: L = xcd + 8*slot; slot -> (pair_local, cb)
    const int L    = blockIdx.x;
    const int xcd  = L & 7;
    const int slot = L >> 3;              // 0..63
    const int gp   = xcd * 16 + (slot >> 2);   // (b,sp) pair, 0..127
    const int cb   = slot & 3;
    const int b    = gp >> 1;
    const int sp   = gp & 1;
    const int c0   = cb * 96;
    const int us   = sp * TH_, ue = us + TH_;

    bf16x8 Ah[6], Al[6];
    const int ar = c0 + w * 16 + tx;
    if (ar < CN_) {
        const u16* yh = Ysh + ((size_t)b * CN_ + ar) * HD_;
        const u16* yl = Ysl + ((size_t)b * CN_ + ar) * HD_;
#pragma unroll
        for (int ks = 0; ks < 6; ks++) {
            Ah[ks] = *(const bf16x8*)(yh + ks * 32 + quad * 8);
            Al[ks] = *(const bf16x8*)(yl + ks * 32 + quad * 8);
        }
    } else {
#pragma unroll
        for (int ks = 0; ks < 6; ks++) { Ah[ks] = (bf16x8)0; Al[ks] = (bf16x8)0; }
    }

    float m_s[4], l_s[4];
    f32x4 accO[12];
#pragma unroll
    for (int r = 0; r < 4; r++) { m_s[r] = -1e30f; l_s[r] = 0.f; }
#pragma unroll
    for (int j = 0; j < 12; j++) accO[j] = (f32x4){0.f, 0.f, 0.f, 0.f};

    const u16* srch = Hh + (size_t)b * T_ * HD_;
    const u16* srcl = Hl + (size_t)b * T_ * HD_;
    const u16* srct = Hth + (size_t)b * HD_ * TP_;

    uint4 pfh[2], pfl[2], pft[2];
    // ---- prologue: issue loads for tile 0 into registers
    {
        const int u0n = us;
#pragma unroll
        for (int i = 0; i < 2; i++) {
            int cid = tid + i * 384;
            int u = cid / 24, c = cid % 24;
            uint4 vh = {0, 0, 0, 0}, vl = {0, 0, 0, 0};
            if (u0n + u < ue) {
                vh = *(const uint4*)(srch + ((size_t)(u0n + u)) * HD_ + c * 8);
                vl = *(const uint4*)(srcl + ((size_t)(u0n + u)) * HD_ + c * 8);
            }
            pfh[i] = vh; pfl[i] = vl;
        }
#pragma unroll
        for (int i = 0; i < 2; i++) {
            int cid = tid + i * 384;
            int h = cid >> 2, cc = cid & 3;
            int ub = u0n + cc * 8;
            uint4 v = {0, 0, 0, 0};
            if (ub + 8 <= ue) {
                v = *(const uint4*)(srct + (size_t)h * TP_ + ub);
            } else if (ub < ue) {
                const u16* p = srct + (size_t)h * TP_;
                u32 w0 = 0, w1 = 0, w2 = 0, w3 = 0;
                if (ub + 0 < ue) w0 |= (u32)p[ub + 0];
                if (ub + 1 < ue) w0 |= (u32)p[ub + 1] << 16;
                if (ub + 2 < ue) w1 |= (u32)p[ub + 2];
                if (ub + 3 < ue) w1 |= (u32)p[ub + 3] << 16;
                if (ub + 4 < ue) w2 |= (u32)p[ub + 4];
                if (ub + 5 < ue) w2 |= (u32)p[ub + 5] << 16;
                if (ub + 6 < ue) w3 |= (u32)p[ub + 6];
                if (ub + 7 < ue) w3 |= (u32)p[ub + 7] << 16;
                v = make_uint4(w0, w1, w2, w3);
            }
            pft[i] = v;
        }
    }

    for (int t = 0; t < 22; t++) {
        const int u0 = us + t * 32;
        __syncthreads();
        // ---- commit prefetched tile to LDS
#pragma unroll
        for (int i = 0; i < 2; i++) {
            int cid = tid + i * 384;
            int u = cid / 24, c = cid % 24;
            *(uint4*)&sHh[u][c * 8] = pfh[i];
            *(uint4*)&sHl[u][c * 8] = pfl[i];
        }
#pragma unroll
        for (int i = 0; i < 2; i++) {
            int cid = tid + i * 384;
            int h = cid >> 2, cc = cid & 3;
            *(uint4*)&sHt[h][cc * 8] = pft[i];
        }
        __syncthreads();

        // ---- issue next tile's loads; latency hides under compute below
        if (t < 21) {
            const int u0n = us + (t + 1) * 32;
#pragma unroll
            for (int i = 0; i < 2; i++) {
                int cid = tid + i * 384;
                int u = cid / 24, c = cid % 24;
                uint4 vh = {0, 0, 0, 0}, vl = {0, 0, 0, 0};
                if (u0n + u < ue) {
                    vh = *(const uint4*)(srch + ((size_t)(u0n + u)) * HD_ + c * 8);
                    vl = *(const uint4*)(srcl + ((size_t)(u0n + u)) * HD_ + c * 8);
                }
                pfh[i] = vh; pfl[i] = vl;
            }
#pragma unroll
            for (int i = 0; i < 2; i++) {
                int cid = tid + i * 384;
                int h = cid >> 2, cc = cid & 3;
                int ub = u0n + cc * 8;
                uint4 v = {0, 0, 0, 0};
                if (ub + 8 <= ue) {
                    v = *(const uint4*)(srct + (size_t)h * TP_ + ub);
                } else if (ub < ue) {
                    const u16* p = srct + (size_t)h * TP_;
                    u32 w0 = 0, w1 = 0, w2 = 0, w3 = 0;
                    if (ub + 0 < ue) w0 |= (u32)p[ub + 0];
                    if (ub + 1 < ue) w0 |= (u32)p[ub + 1] << 16;
                    if (ub + 2 < ue) w1 |= (u32)p[ub + 2];
                    if (ub + 3 < ue) w1 |= (u32)p[ub + 3] << 16;
                    if (ub + 4 < ue) w2 |= (u32)p[ub + 4];
                    if (ub + 5 < ue) w2 |= (u32)p[ub + 5] << 16;
                    if (ub + 6 < ue) w3 |= (u32)p[ub + 6];
                    if (ub + 7 < ue) w3 |= (u32)p[ub + 7] << 16;
                    v = make_uint4(w0, w1, w2, w3);
                }
                pft[i] = v;
            }
        }

        // ---- GEMM1: S[c][u], K=192, split-bf16 (hi*hi + hi*lo + lo*hi)
        f32x4 s0a = {0.f, 0.f, 0.f, 0.f}, s1a = {0.f, 0.f, 0.f, 0.f};
        f32x4 s0b = {0.f, 0.f, 0.f, 0.f}, s1b = {0.f, 0.f, 0.f, 0.f};
        __builtin_amdgcn_s_setprio(1);
#pragma unroll
        for (int ks = 0; ks < 6; ks++) {
            const int kc = ks * 32 + quad * 8;
            bf16x8 bh0 = *(const bf16x8*)&sHh[tx][kc];
            bf16x8 bl0 = *(const bf16x8*)&sHl[tx][kc];
            bf16x8 bh1 = *(const bf16x8*)&sHh[16 + tx][kc];
            bf16x8 bl1 = *(const bf16x8*)&sHl[16 + tx][kc];
            s0a = __builtin_amdgcn_mfma_f32_16x16x32_bf16(Ah[ks], bh0, s0a, 0, 0, 0);
            s1a = __builtin_amdgcn_mfma_f32_16x16x32_bf16(Ah[ks], bl0, s1a, 0, 0, 0);
            s1a = __builtin_amdgcn_mfma_f32_16x16x32_bf16(Al[ks], bh0, s1a, 0, 0, 0);
            s0b = __builtin_amdgcn_mfma_f32_16x16x32_bf16(Ah[ks], bh1, s0b, 0, 0, 0);
            s1b = __builtin_amdgcn_mfma_f32_16x16x32_bf16(Ah[ks], bl1, s1b, 0, 0, 0);
            s1b = __builtin_amdgcn_mfma_f32_16x16x32_bf16(Al[ks], bh1, s1b, 0, 0, 0);
        }
        __builtin_amdgcn_s_setprio(0);
        float sv0[4], sv1[4];
        const bool okA = (u0 + tx) < ue, okB = (u0 + 16 + tx) < ue;
#pragma unroll
        for (int r = 0; r < 4; r++) {
            sv0[r] = okA ? (s0a[r] + s1a[r]) : -1e30f;
            sv1[r] = okB ? (s0b[r] + s1b[r]) : -1e30f;
        }

        // ---- online softmax, fully within-wave (16-lane groups)
        float alpha[4];
#pragma unroll
        for (int r = 0; r < 4; r++) {
            float mx = fmaxf(sv0[r], sv1[r]);
            mx = fmaxf(mx, __shfl_xor(mx, 1));
            mx = fmaxf(mx, __shfl_xor(mx, 2));
            mx = fmaxf(mx, __shfl_xor(mx, 4));
            mx = fmaxf(mx, __shfl_xor(mx, 8));
            float mn = fmaxf(m_s[r], mx);
            alpha[r] = __expf(m_s[r] - mn);
            float p0 = __expf(sv0[r] - mn);
            float p1 = __expf(sv1[r] - mn);
            sP[w * 16 + quad * 4 + r][tx]      = f2bf(p0);
            sP[w * 16 + quad * 4 + r][16 + tx] = f2bf(p1);
            float s = p0 + p1;
            s += __shfl_xor(s, 1);
            s += __shfl_xor(s, 2);
            s += __shfl_xor(s, 4);
            s += __shfl_xor(s, 8);
            l_s[r] = l_s[r] * alpha[r] + s;
            m_s[r] = mn;
        }
        f32x4 alv = {alpha[0], alpha[1], alpha[2], alpha[3]};
#pragma unroll
        for (int j = 0; j < 12; j++) accO[j] *= alv;

        // NOTE: no __syncthreads() here.  sP rows [16w,16w+16) are written
        // and read only by wave w; within-wave in-order DS ops suffice.
        // sHt was staged before the barrier above.

        // ---- PV: O += P * H, K=32 (one MFMA k-step), hi-H only
        bf16x8 pa = *(const bf16x8*)&sP[w * 16 + tx][quad * 8];
        __builtin_amdgcn_s_setprio(1);
#pragma unroll
        for (int j = 0; j < 12; j++) {
            bf16x8 hb = *(const bf16x8*)&sHt[j * 16 + tx][quad * 8];
            accO[j] = __builtin_amdgcn_mfma_f32_16x16x32_bf16(pa, hb, accO[j], 0, 0, 0);
        }
        __builtin_amdgcn_s_setprio(0);
    }

#pragma unroll
    for (int r = 0; r < 4; r++) {
        int c = c0 + w * 16 + quad * 4 + r;
        if (c < CN_) {
            float* orow = Op + (((size_t)sp * B_ + b) * CN_ + c) * HD_;
#pragma unroll
            for (int j = 0; j < 12; j++) orow[j * 16 + tx] = accO[j][r];
            if (tx == 0) {
                size_t mi = ((size_t)sp * B_ + b) * CN_ + c;
                Ml[mi] = m_s[r];
                Ll[mi] = l_s[r];
            }
        }
    }
}

// ---------------------------------------------------------------------------
// K4: merge the two u-half partials.
// ---------------------------------------------------------------------------
__global__ __launch_bounds__(192) void k_merge(const float* __restrict__ Op,
                                               const float* __restrict__ Ml,
                                               const float* __restrict__ Ll,
                                               float* __restrict__ out) {
    const int c = blockIdx.x, b = blockIdx.y, h = threadIdx.x;
    const size_t i0 = (size_t)b * CN_ + c;
    const size_t i1 = (size_t)B_ * CN_ + i0;
    float m0 = Ml[i0], m1 = Ml[i1];
    float l0 = Ll[i0], l1 = Ll[i1];
    float M  = fmaxf(m0, m1);
    float e0 = __expf(m0 - M), e1 = __expf(m1 - M);
    float L  = l0 * e0 + l1 * e1;
    float o0 = Op[i0 * HD_ + h], o1 = Op[i1 * HD_ + h];
    out[i0 * HD_ + h] = (o0 * e0 + o1 * e1) / L;
}

// ---------------------------------------------------------------------------
extern "C" void kernel_launch(void* const* d_in, const int* in_sizes, int n_in,
                              void* d_out, int out_size, void* d_ws, size_t ws_size,
                              hipStream_t stream) {
    const float* X  = (const float*)d_in[0];
    const float* H  = (const float*)d_in[1];
    const float* W1 = (const float*)d_in[2];
    const float* W2 = (const float*)d_in[3];
    float* out = (float*)d_out;

    char* ws = (char*)d_ws;
    u16*   Ysh  = (u16*)(ws);                    //   8,478,720
    u16*   Ysl  = (u16*)(ws + 8478720);          //   8,478,720
    u16*   Hh   = (u16*)(ws + 16957440);         //  33,914,880
    u16*   Hl   = (u16*)(ws + 50872320);         //  33,914,880
    u16*   Hth  = (u16*)(ws + 84787200);         //  34,209,792
    u16*   Xth  = (u16*)(ws + 118996992);        //  17,301,504  (aliased by Op later)
    u16*   Xtl  = (u16*)(ws + 136298496);        //  17,301,504
    float* Op   = (float*)(ws + 118996992);      //  33,914,880  (aliases Xth+Xtl; k12 done first)
    u16*   W2h  = (u16*)(ws + 153600000);        //   1,081,344
    u16*   W2l  = (u16*)(ws + 154681344);        //   1,081,344
    u16*   W1th = (u16*)(ws + 155762688);        //      36,864
    u16*   W1tl = (u16*)(ws + 155799552);        //      36,864
    float* Ml   = (float*)(ws + 155836416);      //     176,640
    float* Ll   = (float*)(ws + 156013056);      //     176,640  -> end 156,189,696

    k0_h    <<<dim3(22, 3, B_), 256, 0, stream>>>(H, Hh, Hl, Hth);
    k0_x    <<<dim3(22, B_),    256, 0, stream>>>(X, Xth, Xtl);
    k0_w2   <<<dim3(1056),      256, 0, stream>>>(W2, W2h, W2l);
    k0_w1   <<<dim3(72),        256, 0, stream>>>(W1, W1th, W1tl);
    k12_mfma<<<dim3(704),       256, 0, stream>>>(W2h, W2l, Xth, Xtl, W1th, W1tl, Ysh, Ysl);
    k3_mfma <<<dim3(512),       384, 0, stream>>>(Ysh, Ysl, Hh, Hl, Hth, Op, Ml, Ll);
    k_merge <<<dim3(CN_, B_),   192, 0, stream>>>(Op, Ml, Ll, out);
}

// Round 4
// 333.202 us; speedup vs baseline: 1.4894x; 1.3753x over previous
//
#include <hip/hip_runtime.h>
#include <math.h>

namespace {
constexpr int B_  = 64;
constexpr int T_  = 1380;
constexpr int XD_ = 96;
constexpr int HD_ = 192;
constexpr int CN_ = 345;
constexpr int CP_ = 384;                       // padded CN
constexpr int TP_ = 1392;                      // padded T for Hth rows
constexpr int TP2_ = 1408;                     // padded T for k12 K-dim (22*64)
constexpr int TH_ = 690;                       // T/2 (u-split in k3)
constexpr float SCALE_ = 0.00736569563735987f; // 1/sqrt(96*192)
}

typedef __attribute__((ext_vector_type(8))) short bf16x8;
typedef __attribute__((ext_vector_type(4))) float f32x4;
typedef unsigned short u16;
typedef unsigned int   u32;

__device__ __forceinline__ u16 f2bf(float f) {
    union { float f; u32 u; } c; c.f = f;
    u32 r = (c.u + 0x7fffu + ((c.u >> 16) & 1u)) >> 16;
    return (u16)r;
}
__device__ __forceinline__ float bf2f(u16 s) {
    union { u32 u; float f; } c; c.u = ((u32)s) << 16;
    return c.f;
}

// ---------------------------------------------------------------------------
// K0h: fused H prep — one read of H produces Hh/Hl ([b][u][h] bf16 hi/lo)
// and Hth ([b][h][u] bf16 hi, row stride TP_).  grid (22, 3, B).
// ---------------------------------------------------------------------------
__global__ __launch_bounds__(256) void k0_h(const float* __restrict__ Hg,
                                            u16* __restrict__ Hh,
                                            u16* __restrict__ Hl,
                                            u16* __restrict__ Hth) {
    __shared__ u16 til[64][68];
    const int tid = threadIdx.x;
    const int u0 = blockIdx.x * 64, h0 = blockIdx.y * 64, b = blockIdx.z;
#pragma unroll
    for (int i = 0; i < 8; i++) {
        int lin = i * 256 + tid;           // 0..2047
        int r = lin >> 5;                  // u row 0..63
        int cp = lin & 31;                 // float2 col
        int u = u0 + r, h = h0 + cp * 2;
        float2 v = make_float2(0.f, 0.f);
        if (u < T_) v = *(const float2*)(Hg + ((size_t)b * T_ + u) * HD_ + h);
        u16 hx = f2bf(v.x), hy = f2bf(v.y);
        u16 lx = f2bf(v.x - bf2f(hx)), ly = f2bf(v.y - bf2f(hy));
        if (u < T_) {
            *(u32*)(Hh + ((size_t)b * T_ + u) * HD_ + h) = (u32)hx | ((u32)hy << 16);
            *(u32*)(Hl + ((size_t)b * T_ + u) * HD_ + h) = (u32)lx | ((u32)ly << 16);
        }
        til[cp * 2][r]     = hx;
        til[cp * 2 + 1][r] = hy;
    }
    __syncthreads();
#pragma unroll
    for (int i = 0; i < 4; i++) {
        int lin = i * 256 + tid;
        int hh = lin >> 4, cc = lin & 15;
        int u = u0 + cc * 4;
        if (u + 4 <= T_) {
            ushort4 v;
            v.x = til[hh][cc * 4 + 0];
            v.y = til[hh][cc * 4 + 1];
            v.z = til[hh][cc * 4 + 2];
            v.w = til[hh][cc * 4 + 3];
            *(ushort4*)(Hth + ((size_t)b * HD_ + h0 + hh) * TP_ + u) = v;
        }
    }
}

// ---------------------------------------------------------------------------
// K0c: X -> Xth/Xtl [b][x][t] bf16 hi/lo, t padded to TP2_ with zeros.
// ---------------------------------------------------------------------------
__global__ __launch_bounds__(256) void k0_x(const float* __restrict__ Xg,
                                            u16* __restrict__ Xth,
                                            u16* __restrict__ Xtl) {
    __shared__ __align__(16) u16 tih[96][72];
    __shared__ __align__(16) u16 til[96][72];
    const int tid = threadIdx.x;
    const int t0 = blockIdx.x * 64, b = blockIdx.y;
#pragma unroll
    for (int i = 0; i < 24; i++) {
        int lin = i * 256 + tid;
        int r = lin / 96, x = lin % 96;
        float v = (t0 + r < T_) ? Xg[((size_t)b * T_ + t0 + r) * XD_ + x] : 0.f;
        u16 hi = f2bf(v);
        tih[x][r] = hi;
        til[x][r] = f2bf(v - bf2f(hi));
    }
    __syncthreads();
#pragma unroll
    for (int i = 0; i < 6; i++) {
        int id = i * 256 + tid;
        int buf = (id >= 768);
        int cid = buf ? id - 768 : id;
        int x = cid >> 3, col = cid & 7;
        uint4 v = *(const uint4*)&(buf ? til : tih)[x][col * 8];
        u16* dst = (buf ? Xtl : Xth) + ((size_t)b * XD_ + x) * TP2_ + t0 + col * 8;
        *(uint4*)dst = v;
    }
}

// ---------------------------------------------------------------------------
// K0d: W2 -> W2h/W2l [CP_][TP2_] bf16 hi/lo, zero padded both dims.
// ---------------------------------------------------------------------------
__global__ __launch_bounds__(256) void k0_w2(const float* __restrict__ W2g,
                                             u16* __restrict__ W2h,
                                             u16* __restrict__ W2l) {
    const int n = CP_ * (TP2_ / 2);
    for (int i = blockIdx.x * 256 + threadIdx.x; i < n; i += gridDim.x * 256) {
        int c = i / (TP2_ / 2), tc = i % (TP2_ / 2);
        int t = tc * 2;
        float v0 = 0.f, v1 = 0.f;
        if (c < CN_) {
            if (t < T_)     v0 = W2g[(size_t)c * T_ + t];
            if (t + 1 < T_) v1 = W2g[(size_t)c * T_ + t + 1];
        }
        u16 h0 = f2bf(v0), h1 = f2bf(v1);
        u16 l0 = f2bf(v0 - bf2f(h0)), l1 = f2bf(v1 - bf2f(h1));
        ((u32*)W2h)[i] = (u32)h0 | ((u32)h1 << 16);
        ((u32*)W2l)[i] = (u32)l0 | ((u32)l1 << 16);
    }
}

// ---------------------------------------------------------------------------
// K0e: W1 [x][h] -> W1th/W1tl [h][x] bf16 hi/lo (tiny).
// ---------------------------------------------------------------------------
__global__ __launch_bounds__(256) void k0_w1(const float* __restrict__ W1g,
                                             u16* __restrict__ W1th,
                                             u16* __restrict__ W1tl) {
    int i = blockIdx.x * 256 + threadIdx.x;
    if (i < HD_ * XD_) {
        int h = i / XD_, x = i % XD_;
        float v = W1g[(size_t)x * HD_ + h];
        u16 hi = f2bf(v);
        W1th[i] = hi;
        W1tl[i] = f2bf(v - bf2f(hi));
    }
}

// ---------------------------------------------------------------------------
// K12: Phase 1 Z[c,x] = W2@X[b] split-bf16 K=1408, Phase 2 Y = SCALE*Z@W1,
// Y stored interleaved u32 (hi|lo<<16), 64B-coalesced.
// c-tile 96, grid 256 = 1 block/CU exactly (96 KB LDS dbuf), 4 waves,
// wave-tile 48x48.  Staging via global_load_lds width=16 (no VGPR staging
// -> no spill), counted vmcnt(12) + raw s_barrier (no full drain).
// LDS rows linear 128B; bank conflicts avoided by XOR-swizzling the
// per-lane GLOBAL source group (g ^= row&7) and applying the same XOR on
// the ds_read side (rule #21: linear dest + inv-swz source + swz read).
// sched_barrier(0) pins each barrier boundary: raw s_barrier is IntrNoMem
// so the compiler could otherwise hoist next-tile gld_lds above it (race).
// ---------------------------------------------------------------------------
__global__ __launch_bounds__(256, 1) void k12_mfma(const u16* __restrict__ W2h,
                                                   const u16* __restrict__ W2l,
                                                   const u16* __restrict__ Xth,
                                                   const u16* __restrict__ Xtl,
                                                   const u16* __restrict__ W1th,
                                                   const u16* __restrict__ W1tl,
                                                   u32* __restrict__ Ysi) {
    __shared__ __align__(16) u16 smem[49152];   // 96 KB = 2 bufs x 4 arrays x 96x64
    float* sZ = (float*)smem;                   // phase 2: 96 x 100 fp32 (38.4 KB, buf0 only)

    const int tid  = threadIdx.x;
    const int lane = tid & 63;
    const int w    = tid >> 6;            // 0..3: wave id == staging array id
    const int tx   = lane & 15;
    const int quad = lane >> 4;
    const int wr   = w >> 1;              // c-half (48 rows)
    const int wc2  = w & 1;               // x-half (48 cols)
    // XCD decode: 4 c-tiles of one b land on one XCD (share X[b] in L2)
    const int L    = blockIdx.x;
    const int xcd  = L & 7;
    const int slot = L >> 3;              // 0..31
    const int b    = xcd * 8 + (slot >> 2);
    const int c0   = (slot & 3) * 96;

    const u16* gsrc;
    size_t rowstart;
    if (w == 0)      { gsrc = W2h; rowstart = (size_t)c0; }
    else if (w == 1) { gsrc = W2l; rowstart = (size_t)c0; }
    else if (w == 2) { gsrc = Xth; rowstart = (size_t)b * XD_; }
    else             { gsrc = Xtl; rowstart = (size_t)b * XD_; }
    const int jg = (lane & 7) ^ ((lane >> 3) & 7);   // pre-swizzled source group

#define STAGE(bufsel, kk)                                                         \
    {                                                                             \
        u16* lb = smem + (bufsel) * 24576 + w * 6144;                             \
        _Pragma("unroll")                                                         \
        for (int i_ = 0; i_ < 12; i_++) {                                         \
            int row_ = i_ * 8 + (lane >> 3);                                      \
            const u16* gp_ = gsrc + (rowstart + row_) * TP2_ + (kk) + jg * 8;     \
            __builtin_amdgcn_global_load_lds(                                     \
                (const __attribute__((address_space(1))) u32*)(const void*)gp_,   \
                (__attribute__((address_space(3))) u32*)(void*)(lb + i_ * 512),   \
                16, 0, 0);                                                        \
        }                                                                         \
    }

    f32x4 accZ[3][3];
#pragma unroll
    for (int i = 0; i < 3; i++)
#pragma unroll
        for (int j = 0; j < 3; j++) accZ[i][j] = (f32x4){0.f, 0.f, 0.f, 0.f};

    STAGE(0, 0);
    for (int s = 0; s < 22; s++) {
        // pin the iteration boundary: nothing below may move above the
        // previous iteration's trailing s_barrier (IntrNoMem!)
        __builtin_amdgcn_sched_barrier(0);
        if (s < 21) {
            STAGE((s + 1) & 1, (s + 1) * 64);
            asm volatile("s_waitcnt vmcnt(12)" ::: "memory");  // cur tile landed
        } else {
            asm volatile("s_waitcnt vmcnt(0)" ::: "memory");
        }
        __builtin_amdgcn_s_barrier();
        __builtin_amdgcn_sched_barrier(0);
        const u16* bufp = smem + (s & 1) * 24576;
#pragma unroll
        for (int ks2 = 0; ks2 < 2; ks2++) {
            const int G = ks2 * 4 + quad;
            bf16x8 ah[3], al[3], bh3[3], bl3[3];
#pragma unroll
            for (int am = 0; am < 3; am++) {
                int row = wr * 48 + am * 16 + tx;
                int off = row * 64 + (G ^ (row & 7)) * 8;
                ah[am] = *(const bf16x8*)(bufp + off);
                al[am] = *(const bf16x8*)(bufp + 6144 + off);
            }
#pragma unroll
            for (int bn = 0; bn < 3; bn++) {
                int row = wc2 * 48 + bn * 16 + tx;
                int off = row * 64 + (G ^ (row & 7)) * 8;
                bh3[bn] = *(const bf16x8*)(bufp + 12288 + off);
                bl3[bn] = *(const bf16x8*)(bufp + 18432 + off);
            }
#pragma unroll
            for (int am = 0; am < 3; am++)
#pragma unroll
                for (int bn = 0; bn < 3; bn++) {
                    accZ[am][bn] = __builtin_amdgcn_mfma_f32_16x16x32_bf16(ah[am], bh3[bn], accZ[am][bn], 0, 0, 0);
                    accZ[am][bn] = __builtin_amdgcn_mfma_f32_16x16x32_bf16(ah[am], bl3[bn], accZ[am][bn], 0, 0, 0);
                    accZ[am][bn] = __builtin_amdgcn_mfma_f32_16x16x32_bf16(al[am], bh3[bn], accZ[am][bn], 0, 0, 0);
                }
        }
        asm volatile("s_waitcnt lgkmcnt(0)" ::: "memory");
        __builtin_amdgcn_sched_barrier(0);
        __builtin_amdgcn_s_barrier();
    }
#undef STAGE

    // ---- phase transition: Z -> LDS (96 x 100 fp32; occupies buf0 region,
    // whose last reads finished two barriers ago)
    __builtin_amdgcn_sched_barrier(0);
#pragma unroll
    for (int am = 0; am < 3; am++)
#pragma unroll
        for (int bn = 0; bn < 3; bn++)
#pragma unroll
            for (int r = 0; r < 4; r++)
                sZ[(wr * 48 + am * 16 + quad * 4 + r) * 100 + wc2 * 48 + bn * 16 + tx] = accZ[am][bn][r];
    __syncthreads();

    bf16x8 A2h[3][3], A2l[3][3];
#pragma unroll
    for (int am = 0; am < 3; am++)
#pragma unroll
        for (int ks = 0; ks < 3; ks++) {
            const float* zrow = sZ + (wr * 48 + am * 16 + tx) * 100 + ks * 32 + quad * 8;
            bf16x8 vh, vl;
#pragma unroll
            for (int j = 0; j < 8; j++) {
                float v = zrow[j];
                u16 hi = f2bf(v);
                vh[j] = (short)hi;
                vl[j] = (short)f2bf(v - bf2f(hi));
            }
            A2h[am][ks] = vh; A2l[am][ks] = vl;
        }

    f32x4 accY[3][6];
#pragma unroll
    for (int i = 0; i < 3; i++)
#pragma unroll
        for (int j = 0; j < 6; j++) accY[i][j] = (f32x4){0.f, 0.f, 0.f, 0.f};
#pragma unroll
    for (int hn = 0; hn < 6; hn++) {
        const int hrow = wc2 * 96 + hn * 16 + tx;
#pragma unroll
        for (int ks = 0; ks < 3; ks++) {
            bf16x8 bh = *(const bf16x8*)(W1th + (size_t)hrow * XD_ + ks * 32 + quad * 8);
            bf16x8 bl = *(const bf16x8*)(W1tl + (size_t)hrow * XD_ + ks * 32 + quad * 8);
#pragma unroll
            for (int am = 0; am < 3; am++) {
                accY[am][hn] = __builtin_amdgcn_mfma_f32_16x16x32_bf16(A2h[am][ks], bh, accY[am][hn], 0, 0, 0);
                accY[am][hn] = __builtin_amdgcn_mfma_f32_16x16x32_bf16(A2h[am][ks], bl, accY[am][hn], 0, 0, 0);
                accY[am][hn] = __builtin_amdgcn_mfma_f32_16x16x32_bf16(A2l[am][ks], bh, accY[am][hn], 0, 0, 0);
            }
        }
    }

    // ---- Y store: interleaved u32 (hi | lo<<16), 16 lanes x 4B = 64B lines
#pragma unroll
    for (int am = 0; am < 3; am++)
#pragma unroll
        for (int r = 0; r < 4; r++) {
            int c = c0 + wr * 48 + am * 16 + quad * 4 + r;
            if (c < CN_) {
                size_t base = ((size_t)b * CN_ + c) * HD_;
#pragma unroll
                for (int hn = 0; hn < 6; hn++) {
                    float y = SCALE_ * accY[am][hn][r];
                    u16 hi = f2bf(y);
                    u16 lo = f2bf(y - bf2f(hi));
                    Ysi[base + wc2 * 96 + hn * 16 + tx] = (u32)hi | ((u32)lo << 16);
                }
            }
        }
}

// ---------------------------------------------------------------------------
// K3: MFMA flash attention over a u-half.  1-D grid 512, block 384 = 6 waves.
// Register-prefetch pipeline for the H staging, 2 barriers/iter, setprio
// around MFMA.  A-operand loaded from interleaved Ysi (unpack once).
// ---------------------------------------------------------------------------
__global__ __launch_bounds__(384, 2) void k3_mfma(const u32* __restrict__ Ysi,
                                                  const u16* __restrict__ Hh,
                                                  const u16* __restrict__ Hl,
                                                  const u16* __restrict__ Hth,
                                                  float* __restrict__ Op,
                                                  float* __restrict__ Ml,
                                                  float* __restrict__ Ll) {
    __shared__ __align__(16) u16 sHh[32][200];
    __shared__ __align__(16) u16 sHl[32][200];
    __shared__ __align__(16) u16 sHt[192][40];
    __shared__ __align__(16) u16 sP[96][40];

    const int tid  = threadIdx.x;
    const int lane = tid & 63;
    const int w    = tid >> 6;            // 0..5
    const int tx   = lane & 15;
    const int quad = lane >> 4;
    const int L    = blockIdx.x;
    const int xcd  = L & 7;
    const int slot = L >> 3;              // 0..63
    const int gp   = xcd * 16 + (slot >> 2);   // (b,sp) pair, 0..127
    const int cb   = slot & 3;
    const int b    = gp >> 1;
    const int sp   = gp & 1;
    const int c0   = cb * 96;
    const int us   = sp * TH_, ue = us + TH_;

    bf16x8 Ah[6], Al[6];
    const int ar = c0 + w * 16 + tx;
    if (ar < CN_) {
        const u32* yi = Ysi + ((size_t)b * CN_ + ar) * HD_;
#pragma unroll
        for (int ks = 0; ks < 6; ks++) {
            u32 vv[8];
            *(uint4*)&vv[0] = *(const uint4*)(yi + ks * 32 + quad * 8);
            *(uint4*)&vv[4] = *(const uint4*)(yi + ks * 32 + quad * 8 + 4);
            bf16x8 hh, ll;
#pragma unroll
            for (int j = 0; j < 8; j++) {
                hh[j] = (short)(vv[j] & 0xffffu);
                ll[j] = (short)(vv[j] >> 16);
            }
            Ah[ks] = hh; Al[ks] = ll;
        }
    } else {
#pragma unroll
        for (int ks = 0; ks < 6; ks++) { Ah[ks] = (bf16x8)0; Al[ks] = (bf16x8)0; }
    }

    float m_s[4], l_s[4];
    f32x4 accO[12];
#pragma unroll
    for (int r = 0; r < 4; r++) { m_s[r] = -1e30f; l_s[r] = 0.f; }
#pragma unroll
    for (int j = 0; j < 12; j++) accO[j] = (f32x4){0.f, 0.f, 0.f, 0.f};

    const u16* srch = Hh + (size_t)b * T_ * HD_;
    const u16* srcl = Hl + (size_t)b * T_ * HD_;
    const u16* srct = Hth + (size_t)b * HD_ * TP_;

    uint4 pfh[2], pfl[2], pft[2];
    // ---- prologue: issue loads for tile 0 into registers
    {
        const int u0n = us;
#pragma unroll
        for (int i = 0; i < 2; i++) {
            int cid = tid + i * 384;
            int u = cid / 24, c = cid % 24;
            uint4 vh = {0, 0, 0, 0}, vl = {0, 0, 0, 0};
            if (u0n + u < ue) {
                vh = *(const uint4*)(srch + ((size_t)(u0n + u)) * HD_ + c * 8);
                vl = *(const uint4*)(srcl + ((size_t)(u0n + u)) * HD_ + c * 8);
            }
            pfh[i] = vh; pfl[i] = vl;
        }
#pragma unroll
        for (int i = 0; i < 2; i++) {
            int cid = tid + i * 384;
            int h = cid >> 2, cc = cid & 3;
            int ub = u0n + cc * 8;
            uint4 v = {0, 0, 0, 0};
            if (ub + 8 <= ue) {
                v = *(const uint4*)(srct + (size_t)h * TP_ + ub);
            } else if (ub < ue) {
                const u16* p = srct + (size_t)h * TP_;
                u32 w0 = 0, w1 = 0, w2 = 0, w3 = 0;
                if (ub + 0 < ue) w0 |= (u32)p[ub + 0];
                if (ub + 1 < ue) w0 |= (u32)p[ub + 1] << 16;
                if (ub + 2 < ue) w1 |= (u32)p[ub + 2];
                if (ub + 3 < ue) w1 |= (u32)p[ub + 3] << 16;
                if (ub + 4 < ue) w2 |= (u32)p[ub + 4];
                if (ub + 5 < ue) w2 |= (u32)p[ub + 5] << 16;
                if (ub + 6 < ue) w3 |= (u32)p[ub + 6];
                if (ub + 7 < ue) w3 |= (u32)p[ub + 7] << 16;
                v = make_uint4(w0, w1, w2, w3);
            }
            pft[i] = v;
        }
    }

    for (int t = 0; t < 22; t++) {
        const int u0 = us + t * 32;
        __syncthreads();
        // ---- commit prefetched tile to LDS
#pragma unroll
        for (int i = 0; i < 2; i++) {
            int cid = tid + i * 384;
            int u = cid / 24, c = cid % 24;
            *(uint4*)&sHh[u][c * 8] = pfh[i];
            *(uint4*)&sHl[u][c * 8] = pfl[i];
        }
#pragma unroll
        for (int i = 0; i < 2; i++) {
            int cid = tid + i * 384;
            int h = cid >> 2, cc = cid & 3;
            *(uint4*)&sHt[h][cc * 8] = pft[i];
        }
        __syncthreads();

        // ---- issue next tile's loads; latency hides under compute below
        if (t < 21) {
            const int u0n = us + (t + 1) * 32;
#pragma unroll
            for (int i = 0; i < 2; i++) {
                int cid = tid + i * 384;
                int u = cid / 24, c = cid % 24;
                uint4 vh = {0, 0, 0, 0}, vl = {0, 0, 0, 0};
                if (u0n + u < ue) {
                    vh = *(const uint4*)(srch + ((size_t)(u0n + u)) * HD_ + c * 8);
                    vl = *(const uint4*)(srcl + ((size_t)(u0n + u)) * HD_ + c * 8);
                }
                pfh[i] = vh; pfl[i] = vl;
            }
#pragma unroll
            for (int i = 0; i < 2; i++) {
                int cid = tid + i * 384;
                int h = cid >> 2, cc = cid & 3;
                int ub = u0n + cc * 8;
                uint4 v = {0, 0, 0, 0};
                if (ub + 8 <= ue) {
                    v = *(const uint4*)(srct + (size_t)h * TP_ + ub);
                } else if (ub < ue) {
                    const u16* p = srct + (size_t)h * TP_;
                    u32 w0 = 0, w1 = 0, w2 = 0, w3 = 0;
                    if (ub + 0 < ue) w0 |= (u32)p[ub + 0];
                    if (ub + 1 < ue) w0 |= (u32)p[ub + 1] << 16;
                    if (ub + 2 < ue) w1 |= (u32)p[ub + 2];
                    if (ub + 3 < ue) w1 |= (u32)p[ub + 3] << 16;
                    if (ub + 4 < ue) w2 |= (u32)p[ub + 4];
                    if (ub + 5 < ue) w2 |= (u32)p[ub + 5] << 16;
                    if (ub + 6 < ue) w3 |= (u32)p[ub + 6];
                    if (ub + 7 < ue) w3 |= (u32)p[ub + 7] << 16;
                    v = make_uint4(w0, w1, w2, w3);
                }
                pft[i] = v;
            }
        }

        // ---- GEMM1: S[c][u], K=192, split-bf16 (hi*hi + hi*lo + lo*hi)
        f32x4 s0a = {0.f, 0.f, 0.f, 0.f}, s1a = {0.f, 0.f, 0.f, 0.f};
        f32x4 s0b = {0.f, 0.f, 0.f, 0.f}, s1b = {0.f, 0.f, 0.f, 0.f};
        __builtin_amdgcn_s_setprio(1);
#pragma unroll
        for (int ks = 0; ks < 6; ks++) {
            const int kc = ks * 32 + quad * 8;
            bf16x8 bh0 = *(const bf16x8*)&sHh[tx][kc];
            bf16x8 bl0 = *(const bf16x8*)&sHl[tx][kc];
            bf16x8 bh1 = *(const bf16x8*)&sHh[16 + tx][kc];
            bf16x8 bl1 = *(const bf16x8*)&sHl[16 + tx][kc];
            s0a = __builtin_amdgcn_mfma_f32_16x16x32_bf16(Ah[ks], bh0, s0a, 0, 0, 0);
            s1a = __builtin_amdgcn_mfma_f32_16x16x32_bf16(Ah[ks], bl0, s1a, 0, 0, 0);
            s1a = __builtin_amdgcn_mfma_f32_16x16x32_bf16(Al[ks], bh0, s1a, 0, 0, 0);
            s0b = __builtin_amdgcn_mfma_f32_16x16x32_bf16(Ah[ks], bh1, s0b, 0, 0, 0);
            s1b = __builtin_amdgcn_mfma_f32_16x16x32_bf16(Ah[ks], bl1, s1b, 0, 0, 0);
            s1b = __builtin_amdgcn_mfma_f32_16x16x32_bf16(Al[ks], bh1, s1b, 0, 0, 0);
        }
        __builtin_amdgcn_s_setprio(0);
        float sv0[4], sv1[4];
        const bool okA = (u0 + tx) < ue, okB = (u0 + 16 + tx) < ue;
#pragma unroll
        for (int r = 0; r < 4; r++) {
            sv0[r] = okA ? (s0a[r] + s1a[r]) : -1e30f;
            sv1[r] = okB ? (s0b[r] + s1b[r]) : -1e30f;
        }

        // ---- online softmax, fully within-wave (16-lane groups)
        float alpha[4];
#pragma unroll
        for (int r = 0; r < 4; r++) {
            float mx = fmaxf(sv0[r], sv1[r]);
            mx = fmaxf(mx, __shfl_xor(mx, 1));
            mx = fmaxf(mx, __shfl_xor(mx, 2));
            mx = fmaxf(mx, __shfl_xor(mx, 4));
            mx = fmaxf(mx, __shfl_xor(mx, 8));
            float mn = fmaxf(m_s[r], mx);
            alpha[r] = __expf(m_s[r] - mn);
            float p0 = __expf(sv0[r] - mn);
            float p1 = __expf(sv1[r] - mn);
            sP[w * 16 + quad * 4 + r][tx]      = f2bf(p0);
            sP[w * 16 + quad * 4 + r][16 + tx] = f2bf(p1);
            float s = p0 + p1;
            s += __shfl_xor(s, 1);
            s += __shfl_xor(s, 2);
            s += __shfl_xor(s, 4);
            s += __shfl_xor(s, 8);
            l_s[r] = l_s[r] * alpha[r] + s;
            m_s[r] = mn;
        }
        f32x4 alv = {alpha[0], alpha[1], alpha[2], alpha[3]};
#pragma unroll
        for (int j = 0; j < 12; j++) accO[j] *= alv;

        // NOTE: no __syncthreads() here.  sP rows [16w,16w+16) are written
        // and read only by wave w; within-wave in-order DS ops suffice.

        // ---- PV: O += P * H, K=32 (one MFMA k-step), hi-H only
        bf16x8 pa = *(const bf16x8*)&sP[w * 16 + tx][quad * 8];
        __builtin_amdgcn_s_setprio(1);
#pragma unroll
        for (int j = 0; j < 12; j++) {
            bf16x8 hb = *(const bf16x8*)&sHt[j * 16 + tx][quad * 8];
            accO[j] = __builtin_amdgcn_mfma_f32_16x16x32_bf16(pa, hb, accO[j], 0, 0, 0);
        }
        __builtin_amdgcn_s_setprio(0);
    }

#pragma unroll
    for (int r = 0; r < 4; r++) {
        int c = c0 + w * 16 + quad * 4 + r;
        if (c < CN_) {
            float* orow = Op + (((size_t)sp * B_ + b) * CN_ + c) * HD_;
#pragma unroll
            for (int j = 0; j < 12; j++) orow[j * 16 + tx] = accO[j][r];
            if (tx == 0) {
                size_t mi = ((size_t)sp * B_ + b) * CN_ + c;
                Ml[mi] = m_s[r];
                Ll[mi] = l_s[r];
            }
        }
    }
}

// ---------------------------------------------------------------------------
// K4: merge the two u-half partials.
// ---------------------------------------------------------------------------
__global__ __launch_bounds__(192) void k_merge(const float* __restrict__ Op,
                                               const float* __restrict__ Ml,
                                               const float* __restrict__ Ll,
                                               float* __restrict__ out) {
    const int c = blockIdx.x, b = blockIdx.y, h = threadIdx.x;
    const size_t i0 = (size_t)b * CN_ + c;
    const size_t i1 = (size_t)B_ * CN_ + i0;
    float m0 = Ml[i0], m1 = Ml[i1];
    float l0 = Ll[i0], l1 = Ll[i1];
    float M  = fmaxf(m0, m1);
    float e0 = __expf(m0 - M), e1 = __expf(m1 - M);
    float L  = l0 * e0 + l1 * e1;
    float o0 = Op[i0 * HD_ + h], o1 = Op[i1 * HD_ + h];
    out[i0 * HD_ + h] = (o0 * e0 + o1 * e1) / L;
}

// ---------------------------------------------------------------------------
extern "C" void kernel_launch(void* const* d_in, const int* in_sizes, int n_in,
                              void* d_out, int out_size, void* d_ws, size_t ws_size,
                              hipStream_t stream) {
    const float* X  = (const float*)d_in[0];
    const float* H  = (const float*)d_in[1];
    const float* W1 = (const float*)d_in[2];
    const float* W2 = (const float*)d_in[3];
    float* out = (float*)d_out;

    char* ws = (char*)d_ws;
    u32*   Ysi  = (u32*)(ws);                    //  16,957,440 (interleaved hi|lo)
    u16*   Hh   = (u16*)(ws + 16957440);         //  33,914,880
    u16*   Hl   = (u16*)(ws + 50872320);         //  33,914,880
    u16*   Hth  = (u16*)(ws + 84787200);         //  34,209,792
    u16*   Xth  = (u16*)(ws + 118996992);        //  17,301,504  (aliased by Op later)
    u16*   Xtl  = (u16*)(ws + 136298496);        //  17,301,504
    float* Op   = (float*)(ws + 118996992);      //  33,914,880  (aliases Xth+Xtl; k12 done first)
    u16*   W2h  = (u16*)(ws + 153600000);        //   1,081,344
    u16*   W2l  = (u16*)(ws + 154681344);        //   1,081,344
    u16*   W1th = (u16*)(ws + 155762688);        //      36,864
    u16*   W1tl = (u16*)(ws + 155799552);        //      36,864
    float* Ml   = (float*)(ws + 155836416);      //     176,640
    float* Ll   = (float*)(ws + 156013056);      //     176,640  -> end 156,189,696

    k0_h    <<<dim3(22, 3, B_), 256, 0, stream>>>(H, Hh, Hl, Hth);
    k0_x    <<<dim3(22, B_),    256, 0, stream>>>(X, Xth, Xtl);
    k0_w2   <<<dim3(1056),      256, 0, stream>>>(W2, W2h, W2l);
    k0_w1   <<<dim3(72),        256, 0, stream>>>(W1, W1th, W1tl);
    k12_mfma<<<dim3(256),       256, 0, stream>>>(W2h, W2l, Xth, Xtl, W1th, W1tl, Ysi);
    k3_mfma <<<dim3(512),       384, 0, stream>>>(Ysi, Hh, Hl, Hth, Op, Ml, Ll);
    k_merge <<<dim3(CN_, B_),   192, 0, stream>>>(Op, Ml, Ll, out);
}

// Round 5
// 315.728 us; speedup vs baseline: 1.5719x; 1.0553x over previous
//
#include <hip/hip_runtime.h>
#include <math.h>

namespace {
constexpr int B_  = 64;
constexpr int T_  = 1380;
constexpr int XD_ = 96;
constexpr int HD_ = 192;
constexpr int CN_ = 345;
constexpr int CP_ = 384;                       // padded CN
constexpr int TP_ = 1392;                      // padded T for Hth rows
constexpr int TP2_ = 1408;                     // padded T for k12 K-dim (22*64)
constexpr int TH_ = 690;                       // T/2 (u-split in k3)
constexpr float SCALE_ = 0.00736569563735987f; // 1/sqrt(96*192)
}

typedef __attribute__((ext_vector_type(8))) short bf16x8;
typedef __attribute__((ext_vector_type(4))) float f32x4;
typedef unsigned short u16;
typedef unsigned int   u32;

__device__ __forceinline__ u16 f2bf(float f) {
    union { float f; u32 u; } c; c.f = f;
    u32 r = (c.u + 0x7fffu + ((c.u >> 16) & 1u)) >> 16;
    return (u16)r;
}
__device__ __forceinline__ float bf2f(u16 s) {
    union { u32 u; float f; } c; c.u = ((u32)s) << 16;
    return c.f;
}

// 16-lane (DPP row) rotate reductions — VALU, not DS pipe (vs __shfl_xor).
__device__ __forceinline__ float red16_max(float v) {
    int ti;
    ti = __builtin_amdgcn_update_dpp(0, __builtin_bit_cast(int, v), 0x128, 0xf, 0xf, true);
    v = fmaxf(v, __builtin_bit_cast(float, ti));
    ti = __builtin_amdgcn_update_dpp(0, __builtin_bit_cast(int, v), 0x124, 0xf, 0xf, true);
    v = fmaxf(v, __builtin_bit_cast(float, ti));
    ti = __builtin_amdgcn_update_dpp(0, __builtin_bit_cast(int, v), 0x122, 0xf, 0xf, true);
    v = fmaxf(v, __builtin_bit_cast(float, ti));
    ti = __builtin_amdgcn_update_dpp(0, __builtin_bit_cast(int, v), 0x121, 0xf, 0xf, true);
    v = fmaxf(v, __builtin_bit_cast(float, ti));
    return v;
}
__device__ __forceinline__ float red16_sum(float v) {
    int ti;
    ti = __builtin_amdgcn_update_dpp(0, __builtin_bit_cast(int, v), 0x128, 0xf, 0xf, true);
    v += __builtin_bit_cast(float, ti);
    ti = __builtin_amdgcn_update_dpp(0, __builtin_bit_cast(int, v), 0x124, 0xf, 0xf, true);
    v += __builtin_bit_cast(float, ti);
    ti = __builtin_amdgcn_update_dpp(0, __builtin_bit_cast(int, v), 0x122, 0xf, 0xf, true);
    v += __builtin_bit_cast(float, ti);
    ti = __builtin_amdgcn_update_dpp(0, __builtin_bit_cast(int, v), 0x121, 0xf, 0xf, true);
    v += __builtin_bit_cast(float, ti);
    return v;
}

// ---------------------------------------------------------------------------
// K0h: fused H prep — one read of H produces Hh/Hl ([b][u][h] bf16 hi/lo)
// and Hth ([b][h][u] bf16 hi, row stride TP_).  grid (22, 3, B).
// ---------------------------------------------------------------------------
__global__ __launch_bounds__(256) void k0_h(const float* __restrict__ Hg,
                                            u16* __restrict__ Hh,
                                            u16* __restrict__ Hl,
                                            u16* __restrict__ Hth) {
    __shared__ u16 til[64][68];
    const int tid = threadIdx.x;
    const int u0 = blockIdx.x * 64, h0 = blockIdx.y * 64, b = blockIdx.z;
#pragma unroll
    for (int i = 0; i < 8; i++) {
        int lin = i * 256 + tid;           // 0..2047
        int r = lin >> 5;                  // u row 0..63
        int cp = lin & 31;                 // float2 col
        int u = u0 + r, h = h0 + cp * 2;
        float2 v = make_float2(0.f, 0.f);
        if (u < T_) v = *(const float2*)(Hg + ((size_t)b * T_ + u) * HD_ + h);
        u16 hx = f2bf(v.x), hy = f2bf(v.y);
        u16 lx = f2bf(v.x - bf2f(hx)), ly = f2bf(v.y - bf2f(hy));
        if (u < T_) {
            *(u32*)(Hh + ((size_t)b * T_ + u) * HD_ + h) = (u32)hx | ((u32)hy << 16);
            *(u32*)(Hl + ((size_t)b * T_ + u) * HD_ + h) = (u32)lx | ((u32)ly << 16);
        }
        til[cp * 2][r]     = hx;
        til[cp * 2 + 1][r] = hy;
    }
    __syncthreads();
#pragma unroll
    for (int i = 0; i < 4; i++) {
        int lin = i * 256 + tid;
        int hh = lin >> 4, cc = lin & 15;
        int u = u0 + cc * 4;
        if (u + 4 <= T_) {
            ushort4 v;
            v.x = til[hh][cc * 4 + 0];
            v.y = til[hh][cc * 4 + 1];
            v.z = til[hh][cc * 4 + 2];
            v.w = til[hh][cc * 4 + 3];
            *(ushort4*)(Hth + ((size_t)b * HD_ + h0 + hh) * TP_ + u) = v;
        }
    }
}

// ---------------------------------------------------------------------------
// K0c: X -> Xth/Xtl [b][x][t] bf16 hi/lo, t padded to TP2_ with zeros.
// ---------------------------------------------------------------------------
__global__ __launch_bounds__(256) void k0_x(const float* __restrict__ Xg,
                                            u16* __restrict__ Xth,
                                            u16* __restrict__ Xtl) {
    __shared__ __align__(16) u16 tih[96][72];
    __shared__ __align__(16) u16 til[96][72];
    const int tid = threadIdx.x;
    const int t0 = blockIdx.x * 64, b = blockIdx.y;
#pragma unroll
    for (int i = 0; i < 24; i++) {
        int lin = i * 256 + tid;
        int r = lin / 96, x = lin % 96;
        float v = (t0 + r < T_) ? Xg[((size_t)b * T_ + t0 + r) * XD_ + x] : 0.f;
        u16 hi = f2bf(v);
        tih[x][r] = hi;
        til[x][r] = f2bf(v - bf2f(hi));
    }
    __syncthreads();
#pragma unroll
    for (int i = 0; i < 6; i++) {
        int id = i * 256 + tid;
        int buf = (id >= 768);
        int cid = buf ? id - 768 : id;
        int x = cid >> 3, col = cid & 7;
        uint4 v = *(const uint4*)&(buf ? til : tih)[x][col * 8];
        u16* dst = (buf ? Xtl : Xth) + ((size_t)b * XD_ + x) * TP2_ + t0 + col * 8;
        *(uint4*)dst = v;
    }
}

// ---------------------------------------------------------------------------
// K0d: W2 -> W2h/W2l [CP_][TP2_] bf16 hi/lo, zero padded both dims.
// ---------------------------------------------------------------------------
__global__ __launch_bounds__(256) void k0_w2(const float* __restrict__ W2g,
                                             u16* __restrict__ W2h,
                                             u16* __restrict__ W2l) {
    const int n = CP_ * (TP2_ / 2);
    for (int i = blockIdx.x * 256 + threadIdx.x; i < n; i += gridDim.x * 256) {
        int c = i / (TP2_ / 2), tc = i % (TP2_ / 2);
        int t = tc * 2;
        float v0 = 0.f, v1 = 0.f;
        if (c < CN_) {
            if (t < T_)     v0 = W2g[(size_t)c * T_ + t];
            if (t + 1 < T_) v1 = W2g[(size_t)c * T_ + t + 1];
        }
        u16 h0 = f2bf(v0), h1 = f2bf(v1);
        u16 l0 = f2bf(v0 - bf2f(h0)), l1 = f2bf(v1 - bf2f(h1));
        ((u32*)W2h)[i] = (u32)h0 | ((u32)h1 << 16);
        ((u32*)W2l)[i] = (u32)l0 | ((u32)l1 << 16);
    }
}

// ---------------------------------------------------------------------------
// K0e: W1 [x][h] -> W1th/W1tl [h][x] bf16 hi/lo (tiny).
// ---------------------------------------------------------------------------
__global__ __launch_bounds__(256) void k0_w1(const float* __restrict__ W1g,
                                             u16* __restrict__ W1th,
                                             u16* __restrict__ W1tl) {
    int i = blockIdx.x * 256 + threadIdx.x;
    if (i < HD_ * XD_) {
        int h = i / XD_, x = i % XD_;
        float v = W1g[(size_t)x * HD_ + h];
        u16 hi = f2bf(v);
        W1th[i] = hi;
        W1tl[i] = f2bf(v - bf2f(hi));
    }
}

// ---------------------------------------------------------------------------
// K12: unchanged from round 4 (passed; gld_lds + counted vmcnt + dbuf).
// ---------------------------------------------------------------------------
__global__ __launch_bounds__(256, 1) void k12_mfma(const u16* __restrict__ W2h,
                                                   const u16* __restrict__ W2l,
                                                   const u16* __restrict__ Xth,
                                                   const u16* __restrict__ Xtl,
                                                   const u16* __restrict__ W1th,
                                                   const u16* __restrict__ W1tl,
                                                   u32* __restrict__ Ysi) {
    __shared__ __align__(16) u16 smem[49152];   // 96 KB = 2 bufs x 4 arrays x 96x64
    float* sZ = (float*)smem;                   // phase 2: 96 x 100 fp32 (38.4 KB, buf0 only)

    const int tid  = threadIdx.x;
    const int lane = tid & 63;
    const int w    = tid >> 6;            // 0..3: wave id == staging array id
    const int tx   = lane & 15;
    const int quad = lane >> 4;
    const int wr   = w >> 1;              // c-half (48 rows)
    const int wc2  = w & 1;               // x-half (48 cols)
    const int L    = blockIdx.x;
    const int xcd  = L & 7;
    const int slot = L >> 3;              // 0..31
    const int b    = xcd * 8 + (slot >> 2);
    const int c0   = (slot & 3) * 96;

    const u16* gsrc;
    size_t rowstart;
    if (w == 0)      { gsrc = W2h; rowstart = (size_t)c0; }
    else if (w == 1) { gsrc = W2l; rowstart = (size_t)c0; }
    else if (w == 2) { gsrc = Xth; rowstart = (size_t)b * XD_; }
    else             { gsrc = Xtl; rowstart = (size_t)b * XD_; }
    const int jg = (lane & 7) ^ ((lane >> 3) & 7);   // pre-swizzled source group

#define STAGE(bufsel, kk)                                                         \
    {                                                                             \
        u16* lb = smem + (bufsel) * 24576 + w * 6144;                             \
        _Pragma("unroll")                                                         \
        for (int i_ = 0; i_ < 12; i_++) {                                         \
            int row_ = i_ * 8 + (lane >> 3);                                      \
            const u16* gp_ = gsrc + (rowstart + row_) * TP2_ + (kk) + jg * 8;     \
            __builtin_amdgcn_global_load_lds(                                     \
                (const __attribute__((address_space(1))) u32*)(const void*)gp_,   \
                (__attribute__((address_space(3))) u32*)(void*)(lb + i_ * 512),   \
                16, 0, 0);                                                        \
        }                                                                         \
    }

    f32x4 accZ[3][3];
#pragma unroll
    for (int i = 0; i < 3; i++)
#pragma unroll
        for (int j = 0; j < 3; j++) accZ[i][j] = (f32x4){0.f, 0.f, 0.f, 0.f};

    STAGE(0, 0);
    for (int s = 0; s < 22; s++) {
        __builtin_amdgcn_sched_barrier(0);
        if (s < 21) {
            STAGE((s + 1) & 1, (s + 1) * 64);
            asm volatile("s_waitcnt vmcnt(12)" ::: "memory");  // cur tile landed
        } else {
            asm volatile("s_waitcnt vmcnt(0)" ::: "memory");
        }
        __builtin_amdgcn_s_barrier();
        __builtin_amdgcn_sched_barrier(0);
        const u16* bufp = smem + (s & 1) * 24576;
#pragma unroll
        for (int ks2 = 0; ks2 < 2; ks2++) {
            const int G = ks2 * 4 + quad;
            bf16x8 ah[3], al[3], bh3[3], bl3[3];
#pragma unroll
            for (int am = 0; am < 3; am++) {
                int row = wr * 48 + am * 16 + tx;
                int off = row * 64 + (G ^ (row & 7)) * 8;
                ah[am] = *(const bf16x8*)(bufp + off);
                al[am] = *(const bf16x8*)(bufp + 6144 + off);
            }
#pragma unroll
            for (int bn = 0; bn < 3; bn++) {
                int row = wc2 * 48 + bn * 16 + tx;
                int off = row * 64 + (G ^ (row & 7)) * 8;
                bh3[bn] = *(const bf16x8*)(bufp + 12288 + off);
                bl3[bn] = *(const bf16x8*)(bufp + 18432 + off);
            }
#pragma unroll
            for (int am = 0; am < 3; am++)
#pragma unroll
                for (int bn = 0; bn < 3; bn++) {
                    accZ[am][bn] = __builtin_amdgcn_mfma_f32_16x16x32_bf16(ah[am], bh3[bn], accZ[am][bn], 0, 0, 0);
                    accZ[am][bn] = __builtin_amdgcn_mfma_f32_16x16x32_bf16(ah[am], bl3[bn], accZ[am][bn], 0, 0, 0);
                    accZ[am][bn] = __builtin_amdgcn_mfma_f32_16x16x32_bf16(al[am], bh3[bn], accZ[am][bn], 0, 0, 0);
                }
        }
        asm volatile("s_waitcnt lgkmcnt(0)" ::: "memory");
        __builtin_amdgcn_sched_barrier(0);
        __builtin_amdgcn_s_barrier();
    }
#undef STAGE

    __builtin_amdgcn_sched_barrier(0);
#pragma unroll
    for (int am = 0; am < 3; am++)
#pragma unroll
        for (int bn = 0; bn < 3; bn++)
#pragma unroll
            for (int r = 0; r < 4; r++)
                sZ[(wr * 48 + am * 16 + quad * 4 + r) * 100 + wc2 * 48 + bn * 16 + tx] = accZ[am][bn][r];
    __syncthreads();

    bf16x8 A2h[3][3], A2l[3][3];
#pragma unroll
    for (int am = 0; am < 3; am++)
#pragma unroll
        for (int ks = 0; ks < 3; ks++) {
            const float* zrow = sZ + (wr * 48 + am * 16 + tx) * 100 + ks * 32 + quad * 8;
            bf16x8 vh, vl;
#pragma unroll
            for (int j = 0; j < 8; j++) {
                float v = zrow[j];
                u16 hi = f2bf(v);
                vh[j] = (short)hi;
                vl[j] = (short)f2bf(v - bf2f(hi));
            }
            A2h[am][ks] = vh; A2l[am][ks] = vl;
        }

    f32x4 accY[3][6];
#pragma unroll
    for (int i = 0; i < 3; i++)
#pragma unroll
        for (int j = 0; j < 6; j++) accY[i][j] = (f32x4){0.f, 0.f, 0.f, 0.f};
#pragma unroll
    for (int hn = 0; hn < 6; hn++) {
        const int hrow = wc2 * 96 + hn * 16 + tx;
#pragma unroll
        for (int ks = 0; ks < 3; ks++) {
            bf16x8 bh = *(const bf16x8*)(W1th + (size_t)hrow * XD_ + ks * 32 + quad * 8);
            bf16x8 bl = *(const bf16x8*)(W1tl + (size_t)hrow * XD_ + ks * 32 + quad * 8);
#pragma unroll
            for (int am = 0; am < 3; am++) {
                accY[am][hn] = __builtin_amdgcn_mfma_f32_16x16x32_bf16(A2h[am][ks], bh, accY[am][hn], 0, 0, 0);
                accY[am][hn] = __builtin_amdgcn_mfma_f32_16x16x32_bf16(A2h[am][ks], bl, accY[am][hn], 0, 0, 0);
                accY[am][hn] = __builtin_amdgcn_mfma_f32_16x16x32_bf16(A2l[am][ks], bh, accY[am][hn], 0, 0, 0);
            }
        }
    }

#pragma unroll
    for (int am = 0; am < 3; am++)
#pragma unroll
        for (int r = 0; r < 4; r++) {
            int c = c0 + wr * 48 + am * 16 + quad * 4 + r;
            if (c < CN_) {
                size_t base = ((size_t)b * CN_ + c) * HD_;
#pragma unroll
                for (int hn = 0; hn < 6; hn++) {
                    float y = SCALE_ * accY[am][hn][r];
                    u16 hi = f2bf(y);
                    u16 lo = f2bf(y - bf2f(hi));
                    Ysi[base + wc2 * 96 + hn * 16 + tx] = (u32)hi | ((u32)lo << 16);
                }
            }
        }
}

// ---------------------------------------------------------------------------
// K3: MFMA flash attention over a u-half.  1-D grid 512, block 384 = 6 waves.
// This round: staging moved to global_load_lds (no ds_writes, no reg
// prefetch) with double-buffered LDS, counted vmcnt(6), raw s_barrier +
// sched_barrier(0) pins (k12's proven idiom).  LDS rows linear; XOR swizzle
// applied to the GLOBAL source chunk and the ds_read side (rule #21):
//   sHh/sHl [32][192]:  chunk c -> c ^ ((u>>1)&7)   (2-way floor on reads)
//   sHt     [192][32]:  chunk c -> c ^ ((h>>2)&3)   (2-way floor)
// Softmax reductions via DPP row_ror (VALU) instead of __shfl_xor (DS pipe).
// Staged garbage beyond ue is harmless: those S entries are masked to -1e30
// so P = 0 and PV contributions vanish.
// LDS: 2x12288(Hh) + 2x12288(Hl) + 2x12288(Ht) + 7680(P) = 81,408 B.
// ---------------------------------------------------------------------------
__global__ __launch_bounds__(384, 2) void k3_mfma(const u32* __restrict__ Ysi,
                                                  const u16* __restrict__ Hh,
                                                  const u16* __restrict__ Hl,
                                                  const u16* __restrict__ Hth,
                                                  float* __restrict__ Op,
                                                  float* __restrict__ Ml,
                                                  float* __restrict__ Ll) {
    __shared__ __align__(16) u16 smem[40704];   // 81,408 B

    const int tid  = threadIdx.x;
    const int lane = tid & 63;
    const int w    = tid >> 6;            // 0..5
    const int tx   = lane & 15;
    const int quad = lane >> 4;
    const int L    = blockIdx.x;
    const int xcd  = L & 7;
    const int slot = L >> 3;              // 0..63
    const int gp   = xcd * 16 + (slot >> 2);   // (b,sp) pair, 0..127
    const int cb   = slot & 3;
    const int b    = gp >> 1;
    const int sp   = gp & 1;
    const int c0   = cb * 96;
    const int us   = sp * TH_, ue = us + TH_;

    // ---- A-operand from interleaved Ysi (unpack once)
    bf16x8 Ah[6], Al[6];
    const int ar = c0 + w * 16 + tx;
    if (ar < CN_) {
        const u32* yi = Ysi + ((size_t)b * CN_ + ar) * HD_;
#pragma unroll
        for (int ks = 0; ks < 6; ks++) {
            u32 vv[8];
            *(uint4*)&vv[0] = *(const uint4*)(yi + ks * 32 + quad * 8);
            *(uint4*)&vv[4] = *(const uint4*)(yi + ks * 32 + quad * 8 + 4);
            bf16x8 hh, ll;
#pragma unroll
            for (int j = 0; j < 8; j++) {
                hh[j] = (short)(vv[j] & 0xffffu);
                ll[j] = (short)(vv[j] >> 16);
            }
            Ah[ks] = hh; Al[ks] = ll;
        }
    } else {
#pragma unroll
        for (int ks = 0; ks < 6; ks++) { Ah[ks] = (bf16x8)0; Al[ks] = (bf16x8)0; }
    }

    float m_s[4], l_s[4];
    f32x4 accO[12];
#pragma unroll
    for (int r = 0; r < 4; r++) { m_s[r] = -1e30f; l_s[r] = 0.f; }
#pragma unroll
    for (int j = 0; j < 12; j++) accO[j] = (f32x4){0.f, 0.f, 0.f, 0.f};

    // ---- per-lane staging descriptors: 36 gld_lds/iter, 6 per wave.
    // insts 0-11: sHh (tile 32u x 24 chunks); 12-23: sHl; 24-35: sHt
    // (192h x 4 chunks).  Source chunk pre-swizzled (involution with read).
    const char* srcp[6];
    u32 off0[6];
    int inc[6];
#pragma unroll
    for (int j = 0; j < 6; j++) {
        int k = w * 6 + j;
        if (k < 24) {
            int arr = (k < 12) ? 0 : 1;
            int ii  = k - arr * 12;
            int cid = ii * 64 + lane;          // 0..767
            int u   = cid / 24, c1 = cid % 24;
            int c   = (c1 & ~7) | ((c1 & 7) ^ ((u >> 1) & 7));
            const u16* basep = (arr == 0 ? Hh : Hl) + (size_t)b * T_ * HD_;
            srcp[j] = (const char*)basep + ((size_t)(us + u) * HD_ + c * 8) * 2;
            inc[j]  = 32 * HD_ * 2;            // 12,288 B per iter
            off0[j] = (u32)(arr * 24576 + ii * 1024);
        } else {
            int ii  = k - 24;
            int cid = ii * 64 + lane;          // 0..767
            int h   = cid >> 2, c2 = cid & 3;
            int c   = c2 ^ ((h >> 2) & 3);
            const u16* basep = Hth + (size_t)b * HD_ * TP_;
            srcp[j] = (const char*)basep + ((size_t)h * TP_ + us + c * 8) * 2;
            inc[j]  = 64;                      // u0 advances 32 -> 64 B
            off0[j] = (u32)(49152 + ii * 1024);
        }
    }

#define STAGE3(bufsel)                                                            \
    {                                                                             \
        _Pragma("unroll")                                                         \
        for (int j_ = 0; j_ < 6; j_++) {                                          \
            __builtin_amdgcn_global_load_lds(                                     \
                (const __attribute__((address_space(1))) u32*)(const void*)srcp[j_], \
                (__attribute__((address_space(3))) u32*)(void*)((char*)smem + off0[j_] + (bufsel) * 12288), \
                16, 0, 0);                                                        \
            srcp[j_] += inc[j_];                                                  \
        }                                                                         \
    }

    u16* sPb = smem + 36864;                   // 96 x 40 u16

    STAGE3(0);                                  // tile 0 -> buf 0
    for (int t = 0; t < 22; t++) {
        const int u0  = us + t * 32;
        const int buf = t & 1;
        __builtin_amdgcn_sched_barrier(0);
        if (t < 21) {
            STAGE3(buf ^ 1);                    // tile t+1 -> other buf
            asm volatile("s_waitcnt vmcnt(6)" ::: "memory");   // tile t landed
        } else {
            asm volatile("s_waitcnt vmcnt(0)" ::: "memory");
        }
        __builtin_amdgcn_s_barrier();
        __builtin_amdgcn_sched_barrier(0);

        const u16* Hhb = smem + buf * 6144;
        const u16* Hlb = smem + 12288 + buf * 6144;
        const u16* Htb = smem + 24576 + buf * 6144;

        // ---- GEMM1: S[c][u], K=192, split-bf16 (hi*hi + hi*lo + lo*hi)
        f32x4 s0a = {0.f, 0.f, 0.f, 0.f}, s1a = {0.f, 0.f, 0.f, 0.f};
        f32x4 s0b = {0.f, 0.f, 0.f, 0.f}, s1b = {0.f, 0.f, 0.f, 0.f};
        const int xr = (tx >> 1) & 7;           // same for row tx and 16+tx
        __builtin_amdgcn_s_setprio(1);
#pragma unroll
        for (int ks = 0; ks < 6; ks++) {
            const int cc = ks * 4 + quad;
            const int cs = (cc & ~7) | ((cc & 7) ^ xr);
            const int ro0 = tx * 192 + cs * 8;
            const int ro1 = (16 + tx) * 192 + cs * 8;
            bf16x8 bh0 = *(const bf16x8*)(Hhb + ro0);
            bf16x8 bl0 = *(const bf16x8*)(Hlb + ro0);
            bf16x8 bh1 = *(const bf16x8*)(Hhb + ro1);
            bf16x8 bl1 = *(const bf16x8*)(Hlb + ro1);
            s0a = __builtin_amdgcn_mfma_f32_16x16x32_bf16(Ah[ks], bh0, s0a, 0, 0, 0);
            s1a = __builtin_amdgcn_mfma_f32_16x16x32_bf16(Ah[ks], bl0, s1a, 0, 0, 0);
            s1a = __builtin_amdgcn_mfma_f32_16x16x32_bf16(Al[ks], bh0, s1a, 0, 0, 0);
            s0b = __builtin_amdgcn_mfma_f32_16x16x32_bf16(Ah[ks], bh1, s0b, 0, 0, 0);
            s1b = __builtin_amdgcn_mfma_f32_16x16x32_bf16(Ah[ks], bl1, s1b, 0, 0, 0);
            s1b = __builtin_amdgcn_mfma_f32_16x16x32_bf16(Al[ks], bh1, s1b, 0, 0, 0);
        }
        __builtin_amdgcn_s_setprio(0);
        float sv0[4], sv1[4];
        const bool okA = (u0 + tx) < ue, okB = (u0 + 16 + tx) < ue;
#pragma unroll
        for (int r = 0; r < 4; r++) {
            sv0[r] = okA ? (s0a[r] + s1a[r]) : -1e30f;
            sv1[r] = okB ? (s0b[r] + s1b[r]) : -1e30f;
        }

        // ---- online softmax; 16-lane reductions via DPP (VALU, no DS)
        float alpha[4];
#pragma unroll
        for (int r = 0; r < 4; r++) {
            float mx = red16_max(fmaxf(sv0[r], sv1[r]));
            float mn = fmaxf(m_s[r], mx);
            alpha[r] = __expf(m_s[r] - mn);
            float p0 = __expf(sv0[r] - mn);
            float p1 = __expf(sv1[r] - mn);
            sPb[(w * 16 + quad * 4 + r) * 40 + tx]      = f2bf(p0);
            sPb[(w * 16 + quad * 4 + r) * 40 + 16 + tx] = f2bf(p1);
            float s = red16_sum(p0 + p1);
            l_s[r] = l_s[r] * alpha[r] + s;
            m_s[r] = mn;
        }
        f32x4 alv = {alpha[0], alpha[1], alpha[2], alpha[3]};
#pragma unroll
        for (int j = 0; j < 12; j++) accO[j] *= alv;

        // ---- PV: O += P * H, K=32.  sP rows are wave-private (in-order DS).
        bf16x8 pa = *(const bf16x8*)(sPb + (w * 16 + tx) * 40 + quad * 8);
        const int ct = quad ^ ((tx >> 2) & 3);
        __builtin_amdgcn_s_setprio(1);
#pragma unroll
        for (int j = 0; j < 12; j++) {
            bf16x8 hb = *(const bf16x8*)(Htb + (j * 16 + tx) * 32 + ct * 8);
            accO[j] = __builtin_amdgcn_mfma_f32_16x16x32_bf16(pa, hb, accO[j], 0, 0, 0);
        }
        __builtin_amdgcn_s_setprio(0);

        // all LDS reads of buf done before any wave stages into it next iter
        asm volatile("s_waitcnt lgkmcnt(0)" ::: "memory");
        __builtin_amdgcn_sched_barrier(0);
        __builtin_amdgcn_s_barrier();
    }
#undef STAGE3

#pragma unroll
    for (int r = 0; r < 4; r++) {
        int c = c0 + w * 16 + quad * 4 + r;
        if (c < CN_) {
            float* orow = Op + (((size_t)sp * B_ + b) * CN_ + c) * HD_;
#pragma unroll
            for (int j = 0; j < 12; j++) orow[j * 16 + tx] = accO[j][r];
            if (tx == 0) {
                size_t mi = ((size_t)sp * B_ + b) * CN_ + c;
                Ml[mi] = m_s[r];
                Ll[mi] = l_s[r];
            }
        }
    }
}

// ---------------------------------------------------------------------------
// K4: merge the two u-half partials.
// ---------------------------------------------------------------------------
__global__ __launch_bounds__(192) void k_merge(const float* __restrict__ Op,
                                               const float* __restrict__ Ml,
                                               const float* __restrict__ Ll,
                                               float* __restrict__ out) {
    const int c = blockIdx.x, b = blockIdx.y, h = threadIdx.x;
    const size_t i0 = (size_t)b * CN_ + c;
    const size_t i1 = (size_t)B_ * CN_ + i0;
    float m0 = Ml[i0], m1 = Ml[i1];
    float l0 = Ll[i0], l1 = Ll[i1];
    float M  = fmaxf(m0, m1);
    float e0 = __expf(m0 - M), e1 = __expf(m1 - M);
    float L  = l0 * e0 + l1 * e1;
    float o0 = Op[i0 * HD_ + h], o1 = Op[i1 * HD_ + h];
    out[i0 * HD_ + h] = (o0 * e0 + o1 * e1) / L;
}

// ---------------------------------------------------------------------------
extern "C" void kernel_launch(void* const* d_in, const int* in_sizes, int n_in,
                              void* d_out, int out_size, void* d_ws, size_t ws_size,
                              hipStream_t stream) {
    const float* X  = (const float*)d_in[0];
    const float* H  = (const float*)d_in[1];
    const float* W1 = (const float*)d_in[2];
    const float* W2 = (const float*)d_in[3];
    float* out = (float*)d_out;

    char* ws = (char*)d_ws;
    u32*   Ysi  = (u32*)(ws);                    //  16,957,440 (interleaved hi|lo)
    u16*   Hh   = (u16*)(ws + 16957440);         //  33,914,880
    u16*   Hl   = (u16*)(ws + 50872320);         //  33,914,880
    u16*   Hth  = (u16*)(ws + 84787200);         //  34,209,792
    u16*   Xth  = (u16*)(ws + 118996992);        //  17,301,504  (aliased by Op later)
    u16*   Xtl  = (u16*)(ws + 136298496);        //  17,301,504
    float* Op   = (float*)(ws + 118996992);      //  33,914,880  (aliases Xth+Xtl; k12 done first)
    u16*   W2h  = (u16*)(ws + 153600000);        //   1,081,344
    u16*   W2l  = (u16*)(ws + 154681344);        //   1,081,344
    u16*   W1th = (u16*)(ws + 155762688);        //      36,864
    u16*   W1tl = (u16*)(ws + 155799552);        //      36,864
    float* Ml   = (float*)(ws + 155836416);      //     176,640
    float* Ll   = (float*)(ws + 156013056);      //     176,640  -> end 156,189,696

    k0_h    <<<dim3(22, 3, B_), 256, 0, stream>>>(H, Hh, Hl, Hth);
    k0_x    <<<dim3(22, B_),    256, 0, stream>>>(X, Xth, Xtl);
    k0_w2   <<<dim3(1056),      256, 0, stream>>>(W2, W2h, W2l);
    k0_w1   <<<dim3(72),        256, 0, stream>>>(W1, W1th, W1tl);
    k12_mfma<<<dim3(256),       256, 0, stream>>>(W2h, W2l, Xth, Xtl, W1th, W1tl, Ysi);
    k3_mfma <<<dim3(512),       384, 0, stream>>>(Ysi, Hh, Hl, Hth, Op, Ml, Ll);
    k_merge <<<dim3(CN_, B_),   192, 0, stream>>>(Op, Ml, Ll, out);
}

// Round 7
// 313.116 us; speedup vs baseline: 1.5850x; 1.0083x over previous
//
#include <hip/hip_runtime.h>
#include <math.h>

namespace {
constexpr int B_  = 64;
constexpr int T_  = 1380;
constexpr int XD_ = 96;
constexpr int HD_ = 192;
constexpr int CN_ = 345;
constexpr int CP_ = 384;                       // padded CN
constexpr int TP_ = 1392;                      // padded T for Hth rows
constexpr int TP2_ = 1408;                     // padded T for k12 K-dim (22*64)
constexpr int TH_ = 690;                       // T/2 (u-split in k3)
constexpr float SCALE_ = 0.00736569563735987f; // 1/sqrt(96*192)
}

typedef __attribute__((ext_vector_type(8))) short bf16x8;
typedef __attribute__((ext_vector_type(4))) float f32x4;
typedef unsigned short u16;
typedef unsigned int   u32;

__device__ __forceinline__ u16 f2bf(float f) {
    union { float f; u32 u; } c; c.f = f;
    u32 r = (c.u + 0x7fffu + ((c.u >> 16) & 1u)) >> 16;
    return (u16)r;
}
__device__ __forceinline__ float bf2f(u16 s) {
    union { u32 u; float f; } c; c.u = ((u32)s) << 16;
    return c.f;
}

// 16-lane (DPP row) rotate reductions — VALU, not DS pipe (vs __shfl_xor).
__device__ __forceinline__ float red16_max(float v) {
    int ti;
    ti = __builtin_amdgcn_update_dpp(0, __builtin_bit_cast(int, v), 0x128, 0xf, 0xf, true);
    v = fmaxf(v, __builtin_bit_cast(float, ti));
    ti = __builtin_amdgcn_update_dpp(0, __builtin_bit_cast(int, v), 0x124, 0xf, 0xf, true);
    v = fmaxf(v, __builtin_bit_cast(float, ti));
    ti = __builtin_amdgcn_update_dpp(0, __builtin_bit_cast(int, v), 0x122, 0xf, 0xf, true);
    v = fmaxf(v, __builtin_bit_cast(float, ti));
    ti = __builtin_amdgcn_update_dpp(0, __builtin_bit_cast(int, v), 0x121, 0xf, 0xf, true);
    v = fmaxf(v, __builtin_bit_cast(float, ti));
    return v;
}
__device__ __forceinline__ float red16_sum(float v) {
    int ti;
    ti = __builtin_amdgcn_update_dpp(0, __builtin_bit_cast(int, v), 0x128, 0xf, 0xf, true);
    v += __builtin_bit_cast(float, ti);
    ti = __builtin_amdgcn_update_dpp(0, __builtin_bit_cast(int, v), 0x124, 0xf, 0xf, true);
    v += __builtin_bit_cast(float, ti);
    ti = __builtin_amdgcn_update_dpp(0, __builtin_bit_cast(int, v), 0x122, 0xf, 0xf, true);
    v += __builtin_bit_cast(float, ti);
    ti = __builtin_amdgcn_update_dpp(0, __builtin_bit_cast(int, v), 0x121, 0xf, 0xf, true);
    v += __builtin_bit_cast(float, ti);
    return v;
}

// ---------------------------------------------------------------------------
// K0h: fused H prep — one read of H produces Hh/Hl ([b][u][h] bf16 hi/lo)
// and Hth ([b][h][u] bf16 hi, row stride TP_).  grid (22, 3, B).
// ---------------------------------------------------------------------------
__global__ __launch_bounds__(256) void k0_h(const float* __restrict__ Hg,
                                            u16* __restrict__ Hh,
                                            u16* __restrict__ Hl,
                                            u16* __restrict__ Hth) {
    __shared__ u16 til[64][68];
    const int tid = threadIdx.x;
    const int u0 = blockIdx.x * 64, h0 = blockIdx.y * 64, b = blockIdx.z;
#pragma unroll
    for (int i = 0; i < 8; i++) {
        int lin = i * 256 + tid;           // 0..2047
        int r = lin >> 5;                  // u row 0..63
        int cp = lin & 31;                 // float2 col
        int u = u0 + r, h = h0 + cp * 2;
        float2 v = make_float2(0.f, 0.f);
        if (u < T_) v = *(const float2*)(Hg + ((size_t)b * T_ + u) * HD_ + h);
        u16 hx = f2bf(v.x), hy = f2bf(v.y);
        u16 lx = f2bf(v.x - bf2f(hx)), ly = f2bf(v.y - bf2f(hy));
        if (u < T_) {
            *(u32*)(Hh + ((size_t)b * T_ + u) * HD_ + h) = (u32)hx | ((u32)hy << 16);
            *(u32*)(Hl + ((size_t)b * T_ + u) * HD_ + h) = (u32)lx | ((u32)ly << 16);
        }
        til[cp * 2][r]     = hx;
        til[cp * 2 + 1][r] = hy;
    }
    __syncthreads();
#pragma unroll
    for (int i = 0; i < 4; i++) {
        int lin = i * 256 + tid;
        int hh = lin >> 4, cc = lin & 15;
        int u = u0 + cc * 4;
        if (u + 4 <= T_) {
            ushort4 v;
            v.x = til[hh][cc * 4 + 0];
            v.y = til[hh][cc * 4 + 1];
            v.z = til[hh][cc * 4 + 2];
            v.w = til[hh][cc * 4 + 3];
            *(ushort4*)(Hth + ((size_t)b * HD_ + h0 + hh) * TP_ + u) = v;
        }
    }
}

// ---------------------------------------------------------------------------
// K0c: X -> Xth/Xtl [b][x][t] bf16 hi/lo, t padded to TP2_ with zeros.
// ---------------------------------------------------------------------------
__global__ __launch_bounds__(256) void k0_x(const float* __restrict__ Xg,
                                            u16* __restrict__ Xth,
                                            u16* __restrict__ Xtl) {
    __shared__ __align__(16) u16 tih[96][72];
    __shared__ __align__(16) u16 til[96][72];
    const int tid = threadIdx.x;
    const int t0 = blockIdx.x * 64, b = blockIdx.y;
#pragma unroll
    for (int i = 0; i < 24; i++) {
        int lin = i * 256 + tid;
        int r = lin / 96, x = lin % 96;
        float v = (t0 + r < T_) ? Xg[((size_t)b * T_ + t0 + r) * XD_ + x] : 0.f;
        u16 hi = f2bf(v);
        tih[x][r] = hi;
        til[x][r] = f2bf(v - bf2f(hi));
    }
    __syncthreads();
#pragma unroll
    for (int i = 0; i < 6; i++) {
        int id = i * 256 + tid;
        int buf = (id >= 768);
        int cid = buf ? id - 768 : id;
        int x = cid >> 3, col = cid & 7;
        uint4 v = *(const uint4*)&(buf ? til : tih)[x][col * 8];
        u16* dst = (buf ? Xtl : Xth) + ((size_t)b * XD_ + x) * TP2_ + t0 + col * 8;
        *(uint4*)dst = v;
    }
}

// ---------------------------------------------------------------------------
// K0d: W2 -> W2h/W2l [CP_][TP2_] bf16 hi/lo, zero padded both dims.
// ---------------------------------------------------------------------------
__global__ __launch_bounds__(256) void k0_w2(const float* __restrict__ W2g,
                                             u16* __restrict__ W2h,
                                             u16* __restrict__ W2l) {
    const int n = CP_ * (TP2_ / 2);
    for (int i = blockIdx.x * 256 + threadIdx.x; i < n; i += gridDim.x * 256) {
        int c = i / (TP2_ / 2), tc = i % (TP2_ / 2);
        int t = tc * 2;
        float v0 = 0.f, v1 = 0.f;
        if (c < CN_) {
            if (t < T_)     v0 = W2g[(size_t)c * T_ + t];
            if (t + 1 < T_) v1 = W2g[(size_t)c * T_ + t + 1];
        }
        u16 h0 = f2bf(v0), h1 = f2bf(v1);
        u16 l0 = f2bf(v0 - bf2f(h0)), l1 = f2bf(v1 - bf2f(h1));
        ((u32*)W2h)[i] = (u32)h0 | ((u32)h1 << 16);
        ((u32*)W2l)[i] = (u32)l0 | ((u32)l1 << 16);
    }
}

// ---------------------------------------------------------------------------
// K0e: W1 [x][h] -> W1th/W1tl [h][x] bf16 hi/lo (tiny).
// ---------------------------------------------------------------------------
__global__ __launch_bounds__(256) void k0_w1(const float* __restrict__ W1g,
                                             u16* __restrict__ W1th,
                                             u16* __restrict__ W1tl) {
    int i = blockIdx.x * 256 + threadIdx.x;
    if (i < HD_ * XD_) {
        int h = i / XD_, x = i % XD_;
        float v = W1g[(size_t)x * HD_ + h];
        u16 hi = f2bf(v);
        W1th[i] = hi;
        W1tl[i] = f2bf(v - bf2f(hi));
    }
}

// ---------------------------------------------------------------------------
// K12: unchanged (passed; gld_lds + counted vmcnt + dbuf).
// ---------------------------------------------------------------------------
__global__ __launch_bounds__(256, 1) void k12_mfma(const u16* __restrict__ W2h,
                                                   const u16* __restrict__ W2l,
                                                   const u16* __restrict__ Xth,
                                                   const u16* __restrict__ Xtl,
                                                   const u16* __restrict__ W1th,
                                                   const u16* __restrict__ W1tl,
                                                   u32* __restrict__ Ysi) {
    __shared__ __align__(16) u16 smem[49152];   // 96 KB = 2 bufs x 4 arrays x 96x64
    float* sZ = (float*)smem;                   // phase 2: 96 x 100 fp32 (38.4 KB, buf0 only)

    const int tid  = threadIdx.x;
    const int lane = tid & 63;
    const int w    = tid >> 6;            // 0..3: wave id == staging array id
    const int tx   = lane & 15;
    const int quad = lane >> 4;
    const int wr   = w >> 1;              // c-half (48 rows)
    const int wc2  = w & 1;               // x-half (48 cols)
    const int L    = blockIdx.x;
    const int xcd  = L & 7;
    const int slot = L >> 3;              // 0..31
    const int b    = xcd * 8 + (slot >> 2);
    const int c0   = (slot & 3) * 96;

    const u16* gsrc;
    size_t rowstart;
    if (w == 0)      { gsrc = W2h; rowstart = (size_t)c0; }
    else if (w == 1) { gsrc = W2l; rowstart = (size_t)c0; }
    else if (w == 2) { gsrc = Xth; rowstart = (size_t)b * XD_; }
    else             { gsrc = Xtl; rowstart = (size_t)b * XD_; }
    const int jg = (lane & 7) ^ ((lane >> 3) & 7);   // pre-swizzled source group

#define STAGE(bufsel, kk)                                                         \
    {                                                                             \
        u16* lb = smem + (bufsel) * 24576 + w * 6144;                             \
        _Pragma("unroll")                                                         \
        for (int i_ = 0; i_ < 12; i_++) {                                         \
            int row_ = i_ * 8 + (lane >> 3);                                      \
            const u16* gp_ = gsrc + (rowstart + row_) * TP2_ + (kk) + jg * 8;     \
            __builtin_amdgcn_global_load_lds(                                     \
                (const __attribute__((address_space(1))) u32*)(const void*)gp_,   \
                (__attribute__((address_space(3))) u32*)(void*)(lb + i_ * 512),   \
                16, 0, 0);                                                        \
        }                                                                         \
    }

    f32x4 accZ[3][3];
#pragma unroll
    for (int i = 0; i < 3; i++)
#pragma unroll
        for (int j = 0; j < 3; j++) accZ[i][j] = (f32x4){0.f, 0.f, 0.f, 0.f};

    STAGE(0, 0);
    for (int s = 0; s < 22; s++) {
        __builtin_amdgcn_sched_barrier(0);
        if (s < 21) {
            STAGE((s + 1) & 1, (s + 1) * 64);
            asm volatile("s_waitcnt vmcnt(12)" ::: "memory");  // cur tile landed
        } else {
            asm volatile("s_waitcnt vmcnt(0)" ::: "memory");
        }
        __builtin_amdgcn_s_barrier();
        __builtin_amdgcn_sched_barrier(0);
        const u16* bufp = smem + (s & 1) * 24576;
#pragma unroll
        for (int ks2 = 0; ks2 < 2; ks2++) {
            const int G = ks2 * 4 + quad;
            bf16x8 ah[3], al[3], bh3[3], bl3[3];
#pragma unroll
            for (int am = 0; am < 3; am++) {
                int row = wr * 48 + am * 16 + tx;
                int off = row * 64 + (G ^ (row & 7)) * 8;
                ah[am] = *(const bf16x8*)(bufp + off);
                al[am] = *(const bf16x8*)(bufp + 6144 + off);
            }
#pragma unroll
            for (int bn = 0; bn < 3; bn++) {
                int row = wc2 * 48 + bn * 16 + tx;
                int off = row * 64 + (G ^ (row & 7)) * 8;
                bh3[bn] = *(const bf16x8*)(bufp + 12288 + off);
                bl3[bn] = *(const bf16x8*)(bufp + 18432 + off);
            }
#pragma unroll
            for (int am = 0; am < 3; am++)
#pragma unroll
                for (int bn = 0; bn < 3; bn++) {
                    accZ[am][bn] = __builtin_amdgcn_mfma_f32_16x16x32_bf16(ah[am], bh3[bn], accZ[am][bn], 0, 0, 0);
                    accZ[am][bn] = __builtin_amdgcn_mfma_f32_16x16x32_bf16(ah[am], bl3[bn], accZ[am][bn], 0, 0, 0);
                    accZ[am][bn] = __builtin_amdgcn_mfma_f32_16x16x32_bf16(al[am], bh3[bn], accZ[am][bn], 0, 0, 0);
                }
        }
        asm volatile("s_waitcnt lgkmcnt(0)" ::: "memory");
        __builtin_amdgcn_sched_barrier(0);
        __builtin_amdgcn_s_barrier();
    }
#undef STAGE

    __builtin_amdgcn_sched_barrier(0);
#pragma unroll
    for (int am = 0; am < 3; am++)
#pragma unroll
        for (int bn = 0; bn < 3; bn++)
#pragma unroll
            for (int r = 0; r < 4; r++)
                sZ[(wr * 48 + am * 16 + quad * 4 + r) * 100 + wc2 * 48 + bn * 16 + tx] = accZ[am][bn][r];
    __syncthreads();

    bf16x8 A2h[3][3], A2l[3][3];
#pragma unroll
    for (int am = 0; am < 3; am++)
#pragma unroll
        for (int ks = 0; ks < 3; ks++) {
            const float* zrow = sZ + (wr * 48 + am * 16 + tx) * 100 + ks * 32 + quad * 8;
            bf16x8 vh, vl;
#pragma unroll
            for (int j = 0; j < 8; j++) {
                float v = zrow[j];
                u16 hi = f2bf(v);
                vh[j] = (short)hi;
                vl[j] = (short)f2bf(v - bf2f(hi));
            }
            A2h[am][ks] = vh; A2l[am][ks] = vl;
        }

    f32x4 accY[3][6];
#pragma unroll
    for (int i = 0; i < 3; i++)
#pragma unroll
        for (int j = 0; j < 6; j++) accY[i][j] = (f32x4){0.f, 0.f, 0.f, 0.f};
#pragma unroll
    for (int hn = 0; hn < 6; hn++) {
        const int hrow = wc2 * 96 + hn * 16 + tx;
#pragma unroll
        for (int ks = 0; ks < 3; ks++) {
            bf16x8 bh = *(const bf16x8*)(W1th + (size_t)hrow * XD_ + ks * 32 + quad * 8);
            bf16x8 bl = *(const bf16x8*)(W1tl + (size_t)hrow * XD_ + ks * 32 + quad * 8);
#pragma unroll
            for (int am = 0; am < 3; am++) {
                accY[am][hn] = __builtin_amdgcn_mfma_f32_16x16x32_bf16(A2h[am][ks], bh, accY[am][hn], 0, 0, 0);
                accY[am][hn] = __builtin_amdgcn_mfma_f32_16x16x32_bf16(A2h[am][ks], bl, accY[am][hn], 0, 0, 0);
                accY[am][hn] = __builtin_amdgcn_mfma_f32_16x16x32_bf16(A2l[am][ks], bh, accY[am][hn], 0, 0, 0);
            }
        }
    }

#pragma unroll
    for (int am = 0; am < 3; am++)
#pragma unroll
        for (int r = 0; r < 4; r++) {
            int c = c0 + wr * 48 + am * 16 + quad * 4 + r;
            if (c < CN_) {
                size_t base = ((size_t)b * CN_ + c) * HD_;
#pragma unroll
                for (int hn = 0; hn < 6; hn++) {
                    float y = SCALE_ * accY[am][hn][r];
                    u16 hi = f2bf(y);
                    u16 lo = f2bf(y - bf2f(hi));
                    Ysi[base + wc2 * 96 + hn * 16 + tx] = (u32)hi | ((u32)lo << 16);
                }
            }
        }
}

// ---------------------------------------------------------------------------
// K3: MFMA flash attention over a u-half.  1-D grid 512, block 384 = 6 waves.
// Register diet for 2-blocks/CU residency: __launch_bounds__(384,3)
// (cap ~170 unified regs = 3 waves/SIMD = 2 blocks/CU), wave-uniform
// staging offsets forced to SGPRs (readfirstlane), single per-wave scalar
// stride.  Structure otherwise identical to the round-5 kernel (passed).
// ---------------------------------------------------------------------------
__global__ __launch_bounds__(384, 3) void k3_mfma(const u32* __restrict__ Ysi,
                                                  const u16* __restrict__ Hh,
                                                  const u16* __restrict__ Hl,
                                                  const u16* __restrict__ Hth,
                                                  float* __restrict__ Op,
                                                  float* __restrict__ Ml,
                                                  float* __restrict__ Ll) {
    __shared__ __align__(16) u16 smem[40704];   // 81,408 B (2 blocks = 162,816 <= 163,840)

    const int tid  = threadIdx.x;
    const int lane = tid & 63;
    const int w    = tid >> 6;            // 0..5
    const int tx   = lane & 15;
    const int quad = lane >> 4;
    const int L    = blockIdx.x;
    const int xcd  = L & 7;
    const int slot = L >> 3;              // 0..63
    const int gp   = xcd * 16 + (slot >> 2);   // (b,sp) pair, 0..127
    const int cb   = slot & 3;
    const int b    = gp >> 1;
    const int sp   = gp & 1;
    const int c0   = cb * 96;
    const int us   = sp * TH_, ue = us + TH_;

    // ---- A-operand from interleaved Ysi (unpack once)
    bf16x8 Ah[6], Al[6];
    const int ar = c0 + w * 16 + tx;
    if (ar < CN_) {
        const u32* yi = Ysi + ((size_t)b * CN_ + ar) * HD_;
#pragma unroll
        for (int ks = 0; ks < 6; ks++) {
            u32 vv[8];
            *(uint4*)&vv[0] = *(const uint4*)(yi + ks * 32 + quad * 8);
            *(uint4*)&vv[4] = *(const uint4*)(yi + ks * 32 + quad * 8 + 4);
            bf16x8 hh, ll;
#pragma unroll
            for (int j = 0; j < 8; j++) {
                hh[j] = (short)(vv[j] & 0xffffu);
                ll[j] = (short)(vv[j] >> 16);
            }
            Ah[ks] = hh; Al[ks] = ll;
        }
    } else {
#pragma unroll
        for (int ks = 0; ks < 6; ks++) { Ah[ks] = (bf16x8)0; Al[ks] = (bf16x8)0; }
    }

    float m_s[4], l_s[4];
    f32x4 accO[12];
#pragma unroll
    for (int r = 0; r < 4; r++) { m_s[r] = -1e30f; l_s[r] = 0.f; }
#pragma unroll
    for (int j = 0; j < 12; j++) accO[j] = (f32x4){0.f, 0.f, 0.f, 0.f};

    // ---- per-lane staging descriptors: 36 gld_lds/iter, 6 per wave.
    // insts 0-11: sHh (tile 32u x 24 chunks); 12-23: sHl; 24-35: sHt
    // (192h x 4 chunks).  Source chunk pre-swizzled (involution with read).
    // off0 / incw are wave-uniform -> forced into SGPRs.
    const char* srcp[6];
    u32 off0[6];
    const u32 incw = (u32)__builtin_amdgcn_readfirstlane((w < 4) ? (32 * HD_ * 2) : 64);
#pragma unroll
    for (int j = 0; j < 6; j++) {
        int k = w * 6 + j;
        u32 o;
        if (k < 24) {
            int arr = (k < 12) ? 0 : 1;
            int ii  = k - arr * 12;
            int cid = ii * 64 + lane;          // 0..767
            int u   = cid / 24, c1 = cid % 24;
            int c   = (c1 & ~7) | ((c1 & 7) ^ ((u >> 1) & 7));
            const u16* basep = (arr == 0 ? Hh : Hl) + (size_t)b * T_ * HD_;
            srcp[j] = (const char*)basep + ((size_t)(us + u) * HD_ + c * 8) * 2;
            o = (u32)(arr * 24576 + ii * 1024);
        } else {
            int ii  = k - 24;
            int cid = ii * 64 + lane;          // 0..767
            int h   = cid >> 2, c2 = cid & 3;
            int c   = c2 ^ ((h >> 2) & 3);
            const u16* basep = Hth + (size_t)b * HD_ * TP_;
            srcp[j] = (const char*)basep + ((size_t)h * TP_ + us + c * 8) * 2;
            o = (u32)(49152 + ii * 1024);
        }
        off0[j] = (u32)__builtin_amdgcn_readfirstlane((int)o);
    }

#define STAGE3(bufsel)                                                            \
    {                                                                             \
        _Pragma("unroll")                                                         \
        for (int j_ = 0; j_ < 6; j_++) {                                          \
            __builtin_amdgcn_global_load_lds(                                     \
                (const __attribute__((address_space(1))) u32*)(const void*)srcp[j_], \
                (__attribute__((address_space(3))) u32*)(void*)((char*)smem + off0[j_] + (bufsel) * 12288), \
                16, 0, 0);                                                        \
            srcp[j_] += incw;                                                     \
        }                                                                         \
    }

    u16* sPb = smem + 36864;                   // 96 x 40 u16

    STAGE3(0);                                  // tile 0 -> buf 0
    for (int t = 0; t < 22; t++) {
        const int u0  = us + t * 32;
        const int buf = t & 1;
        __builtin_amdgcn_sched_barrier(0);
        if (t < 21) {
            STAGE3(buf ^ 1);                    // tile t+1 -> other buf
            asm volatile("s_waitcnt vmcnt(6)" ::: "memory");   // tile t landed
        } else {
            asm volatile("s_waitcnt vmcnt(0)" ::: "memory");
        }
        __builtin_amdgcn_s_barrier();
        __builtin_amdgcn_sched_barrier(0);

        const u16* Hhb = smem + buf * 6144;
        const u16* Hlb = smem + 12288 + buf * 6144;
        const u16* Htb = smem + 24576 + buf * 6144;

        // ---- GEMM1: S[c][u], K=192, split-bf16 (hi*hi + hi*lo + lo*hi)
        f32x4 s0a = {0.f, 0.f, 0.f, 0.f}, s1a = {0.f, 0.f, 0.f, 0.f};
        f32x4 s0b = {0.f, 0.f, 0.f, 0.f}, s1b = {0.f, 0.f, 0.f, 0.f};
        const int xr = (tx >> 1) & 7;           // same for row tx and 16+tx
        __builtin_amdgcn_s_setprio(1);
#pragma unroll
        for (int ks = 0; ks < 6; ks++) {
            const int cc = ks * 4 + quad;
            const int cs = (cc & ~7) | ((cc & 7) ^ xr);
            const int ro0 = tx * 192 + cs * 8;
            const int ro1 = (16 + tx) * 192 + cs * 8;
            bf16x8 bh0 = *(const bf16x8*)(Hhb + ro0);
            bf16x8 bl0 = *(const bf16x8*)(Hlb + ro0);
            bf16x8 bh1 = *(const bf16x8*)(Hhb + ro1);
            bf16x8 bl1 = *(const bf16x8*)(Hlb + ro1);
            s0a = __builtin_amdgcn_mfma_f32_16x16x32_bf16(Ah[ks], bh0, s0a, 0, 0, 0);
            s1a = __builtin_amdgcn_mfma_f32_16x16x32_bf16(Ah[ks], bl0, s1a, 0, 0, 0);
            s1a = __builtin_amdgcn_mfma_f32_16x16x32_bf16(Al[ks], bh0, s1a, 0, 0, 0);
            s0b = __builtin_amdgcn_mfma_f32_16x16x32_bf16(Ah[ks], bh1, s0b, 0, 0, 0);
            s1b = __builtin_amdgcn_mfma_f32_16x16x32_bf16(Ah[ks], bl1, s1b, 0, 0, 0);
            s1b = __builtin_amdgcn_mfma_f32_16x16x32_bf16(Al[ks], bh1, s1b, 0, 0, 0);
        }
        __builtin_amdgcn_s_setprio(0);
        float sv0[4], sv1[4];
        const bool okA = (u0 + tx) < ue, okB = (u0 + 16 + tx) < ue;
#pragma unroll
        for (int r = 0; r < 4; r++) {
            sv0[r] = okA ? (s0a[r] + s1a[r]) : -1e30f;
            sv1[r] = okB ? (s0b[r] + s1b[r]) : -1e30f;
        }

        // ---- online softmax; 16-lane reductions via DPP (VALU, no DS)
        float alpha[4];
#pragma unroll
        for (int r = 0; r < 4; r++) {
            float mx = red16_max(fmaxf(sv0[r], sv1[r]));
            float mn = fmaxf(m_s[r], mx);
            alpha[r] = __expf(m_s[r] - mn);
            float p0 = __expf(sv0[r] - mn);
            float p1 = __expf(sv1[r] - mn);
            sPb[(w * 16 + quad * 4 + r) * 40 + tx]      = f2bf(p0);
            sPb[(w * 16 + quad * 4 + r) * 40 + 16 + tx] = f2bf(p1);
            float s = red16_sum(p0 + p1);
            l_s[r] = l_s[r] * alpha[r] + s;
            m_s[r] = mn;
        }
        f32x4 alv = {alpha[0], alpha[1], alpha[2], alpha[3]};
#pragma unroll
        for (int j = 0; j < 12; j++) accO[j] *= alv;

        // ---- PV: O += P * H, K=32.  sP rows are wave-private (in-order DS).
        bf16x8 pa = *(const bf16x8*)(sPb + (w * 16 + tx) * 40 + quad * 8);
        const int ct = quad ^ ((tx >> 2) & 3);
        __builtin_amdgcn_s_setprio(1);
#pragma unroll
        for (int j = 0; j < 12; j++) {
            bf16x8 hb = *(const bf16x8*)(Htb + (j * 16 + tx) * 32 + ct * 8);
            accO[j] = __builtin_amdgcn_mfma_f32_16x16x32_bf16(pa, hb, accO[j], 0, 0, 0);
        }
        __builtin_amdgcn_s_setprio(0);

        // all LDS reads of buf done before any wave stages into it next iter
        asm volatile("s_waitcnt lgkmcnt(0)" ::: "memory");
        __builtin_amdgcn_sched_barrier(0);
        __builtin_amdgcn_s_barrier();
    }
#undef STAGE3

#pragma unroll
    for (int r = 0; r < 4; r++) {
        int c = c0 + w * 16 + quad * 4 + r;
        if (c < CN_) {
            float* orow = Op + (((size_t)sp * B_ + b) * CN_ + c) * HD_;
#pragma unroll
            for (int j = 0; j < 12; j++) orow[j * 16 + tx] = accO[j][r];
            if (tx == 0) {
                size_t mi = ((size_t)sp * B_ + b) * CN_ + c;
                Ml[mi] = m_s[r];
                Ll[mi] = l_s[r];
            }
        }
    }
}

// ---------------------------------------------------------------------------
// K4: merge the two u-half partials.
// ---------------------------------------------------------------------------
__global__ __launch_bounds__(192) void k_merge(const float* __restrict__ Op,
                                               const float* __restrict__ Ml,
                                               const float* __restrict__ Ll,
                                               float* __restrict__ out) {
    const int c = blockIdx.x, b = blockIdx.y, h = threadIdx.x;
    const size_t i0 = (size_t)b * CN_ + c;
    const size_t i1 = (size_t)B_ * CN_ + i0;
    float m0 = Ml[i0], m1 = Ml[i1];
    float l0 = Ll[i0], l1 = Ll[i1];
    float M  = fmaxf(m0, m1);
    float e0 = __expf(m0 - M), e1 = __expf(m1 - M);
    float L  = l0 * e0 + l1 * e1;
    float o0 = Op[i0 * HD_ + h], o1 = Op[i1 * HD_ + h];
    out[i0 * HD_ + h] = (o0 * e0 + o1 * e1) / L;
}

// ---------------------------------------------------------------------------
extern "C" void kernel_launch(void* const* d_in, const int* in_sizes, int n_in,
                              void* d_out, int out_size, void* d_ws, size_t ws_size,
                              hipStream_t stream) {
    const float* X  = (const float*)d_in[0];
    const float* H  = (const float*)d_in[1];
    const float* W1 = (const float*)d_in[2];
    const float* W2 = (const float*)d_in[3];
    float* out = (float*)d_out;

    char* ws = (char*)d_ws;
    u32*   Ysi  = (u32*)(ws);                    //  16,957,440 (interleaved hi|lo)
    u16*   Hh   = (u16*)(ws + 16957440);         //  33,914,880
    u16*   Hl   = (u16*)(ws + 50872320);         //  33,914,880
    u16*   Hth  = (u16*)(ws + 84787200);         //  34,209,792
    u16*   Xth  = (u16*)(ws + 118996992);        //  17,301,504  (aliased by Op later)
    u16*   Xtl  = (u16*)(ws + 136298496);        //  17,301,504
    float* Op   = (float*)(ws + 118996992);      //  33,914,880  (aliases Xth+Xtl; k12 done first)
    u16*   W2h  = (u16*)(ws + 153600000);        //   1,081,344
    u16*   W2l  = (u16*)(ws + 154681344);        //   1,081,344
    u16*   W1th = (u16*)(ws + 155762688);        //      36,864
    u16*   W1tl = (u16*)(ws + 155799552);        //      36,864
    float* Ml   = (float*)(ws + 155836416);      //     176,640
    float* Ll   = (float*)(ws + 156013056);      //     176,640  -> end 156,189,696

    k0_h    <<<dim3(22, 3, B_), 256, 0, stream>>>(H, Hh, Hl, Hth);
    k0_x    <<<dim3(22, B_),    256, 0, stream>>>(X, Xth, Xtl);
    k0_w2   <<<dim3(1056),      256, 0, stream>>>(W2, W2h, W2l);
    k0_w1   <<<dim3(72),        256, 0, stream>>>(W1, W1th, W1tl);
    k12_mfma<<<dim3(256),       256, 0, stream>>>(W2h, W2l, Xth, Xtl, W1th, W1tl, Ysi);
    k3_mfma <<<dim3(512),       384, 0, stream>>>(Ysi, Hh, Hl, Hth, Op, Ml, Ll);
    k_merge <<<dim3(CN_, B_),   192, 0, stream>>>(Op, Ml, Ll, out);
}

// Round 8
// 284.600 us; speedup vs baseline: 1.7438x; 1.1002x over previous
//
#include <hip/hip_runtime.h>
#include <math.h>

namespace {
constexpr int B_  = 64;
constexpr int T_  = 1380;
constexpr int XD_ = 96;
constexpr int HD_ = 192;
constexpr int CN_ = 345;
constexpr int CP_ = 384;                       // padded CN
constexpr int TP_ = 1392;                      // padded T for Hth rows
constexpr int TP2_ = 1408;                     // padded T for k12 K-dim (22*64)
constexpr int TH_ = 690;                       // T/2 (u-split in k3)
constexpr float SCALE_ = 0.00736569563735987f; // 1/sqrt(96*192)
}

typedef __attribute__((ext_vector_type(8))) short bf16x8;
typedef __attribute__((ext_vector_type(4))) float f32x4;
typedef unsigned short u16;
typedef unsigned int   u32;

__device__ __forceinline__ u16 f2bf(float f) {
    union { float f; u32 u; } c; c.f = f;
    u32 r = (c.u + 0x7fffu + ((c.u >> 16) & 1u)) >> 16;
    return (u16)r;
}
__device__ __forceinline__ float bf2f(u16 s) {
    union { u32 u; float f; } c; c.u = ((u32)s) << 16;
    return c.f;
}

// 16-lane (DPP row) rotate reductions — VALU, not DS pipe (vs __shfl_xor).
__device__ __forceinline__ float red16_max(float v) {
    int ti;
    ti = __builtin_amdgcn_update_dpp(0, __builtin_bit_cast(int, v), 0x128, 0xf, 0xf, true);
    v = fmaxf(v, __builtin_bit_cast(float, ti));
    ti = __builtin_amdgcn_update_dpp(0, __builtin_bit_cast(int, v), 0x124, 0xf, 0xf, true);
    v = fmaxf(v, __builtin_bit_cast(float, ti));
    ti = __builtin_amdgcn_update_dpp(0, __builtin_bit_cast(int, v), 0x122, 0xf, 0xf, true);
    v = fmaxf(v, __builtin_bit_cast(float, ti));
    ti = __builtin_amdgcn_update_dpp(0, __builtin_bit_cast(int, v), 0x121, 0xf, 0xf, true);
    v = fmaxf(v, __builtin_bit_cast(float, ti));
    return v;
}
__device__ __forceinline__ float red16_sum(float v) {
    int ti;
    ti = __builtin_amdgcn_update_dpp(0, __builtin_bit_cast(int, v), 0x128, 0xf, 0xf, true);
    v += __builtin_bit_cast(float, ti);
    ti = __builtin_amdgcn_update_dpp(0, __builtin_bit_cast(int, v), 0x124, 0xf, 0xf, true);
    v += __builtin_bit_cast(float, ti);
    ti = __builtin_amdgcn_update_dpp(0, __builtin_bit_cast(int, v), 0x122, 0xf, 0xf, true);
    v += __builtin_bit_cast(float, ti);
    ti = __builtin_amdgcn_update_dpp(0, __builtin_bit_cast(int, v), 0x121, 0xf, 0xf, true);
    v += __builtin_bit_cast(float, ti);
    return v;
}

// ---------------------------------------------------------------------------
// K0h: fused H prep — one read of H produces Hh/Hl ([b][u][h] bf16 hi/lo)
// and Hth ([b][h][u] bf16 hi, row stride TP_).  grid (22, 3, B).
// ---------------------------------------------------------------------------
__global__ __launch_bounds__(256) void k0_h(const float* __restrict__ Hg,
                                            u16* __restrict__ Hh,
                                            u16* __restrict__ Hl,
                                            u16* __restrict__ Hth) {
    __shared__ u16 til[64][68];
    const int tid = threadIdx.x;
    const int u0 = blockIdx.x * 64, h0 = blockIdx.y * 64, b = blockIdx.z;
#pragma unroll
    for (int i = 0; i < 8; i++) {
        int lin = i * 256 + tid;           // 0..2047
        int r = lin >> 5;                  // u row 0..63
        int cp = lin & 31;                 // float2 col
        int u = u0 + r, h = h0 + cp * 2;
        float2 v = make_float2(0.f, 0.f);
        if (u < T_) v = *(const float2*)(Hg + ((size_t)b * T_ + u) * HD_ + h);
        u16 hx = f2bf(v.x), hy = f2bf(v.y);
        u16 lx = f2bf(v.x - bf2f(hx)), ly = f2bf(v.y - bf2f(hy));
        if (u < T_) {
            *(u32*)(Hh + ((size_t)b * T_ + u) * HD_ + h) = (u32)hx | ((u32)hy << 16);
            *(u32*)(Hl + ((size_t)b * T_ + u) * HD_ + h) = (u32)lx | ((u32)ly << 16);
        }
        til[cp * 2][r]     = hx;
        til[cp * 2 + 1][r] = hy;
    }
    __syncthreads();
#pragma unroll
    for (int i = 0; i < 4; i++) {
        int lin = i * 256 + tid;
        int hh = lin >> 4, cc = lin & 15;
        int u = u0 + cc * 4;
        if (u + 4 <= T_) {
            ushort4 v;
            v.x = til[hh][cc * 4 + 0];
            v.y = til[hh][cc * 4 + 1];
            v.z = til[hh][cc * 4 + 2];
            v.w = til[hh][cc * 4 + 3];
            *(ushort4*)(Hth + ((size_t)b * HD_ + h0 + hh) * TP_ + u) = v;
        }
    }
}

// ---------------------------------------------------------------------------
// K0c: X -> Xth/Xtl [b][x][t] bf16 hi/lo, t padded to TP2_ with zeros.
// ---------------------------------------------------------------------------
__global__ __launch_bounds__(256) void k0_x(const float* __restrict__ Xg,
                                            u16* __restrict__ Xth,
                                            u16* __restrict__ Xtl) {
    __shared__ __align__(16) u16 tih[96][72];
    __shared__ __align__(16) u16 til[96][72];
    const int tid = threadIdx.x;
    const int t0 = blockIdx.x * 64, b = blockIdx.y;
#pragma unroll
    for (int i = 0; i < 24; i++) {
        int lin = i * 256 + tid;
        int r = lin / 96, x = lin % 96;
        float v = (t0 + r < T_) ? Xg[((size_t)b * T_ + t0 + r) * XD_ + x] : 0.f;
        u16 hi = f2bf(v);
        tih[x][r] = hi;
        til[x][r] = f2bf(v - bf2f(hi));
    }
    __syncthreads();
#pragma unroll
    for (int i = 0; i < 6; i++) {
        int id = i * 256 + tid;
        int buf = (id >= 768);
        int cid = buf ? id - 768 : id;
        int x = cid >> 3, col = cid & 7;
        uint4 v = *(const uint4*)&(buf ? til : tih)[x][col * 8];
        u16* dst = (buf ? Xtl : Xth) + ((size_t)b * XD_ + x) * TP2_ + t0 + col * 8;
        *(uint4*)dst = v;
    }
}

// ---------------------------------------------------------------------------
// K0d: W2 -> W2h/W2l [CP_][TP2_] bf16 hi/lo, zero padded both dims.
// ---------------------------------------------------------------------------
__global__ __launch_bounds__(256) void k0_w2(const float* __restrict__ W2g,
                                             u16* __restrict__ W2h,
                                             u16* __restrict__ W2l) {
    const int n = CP_ * (TP2_ / 2);
    for (int i = blockIdx.x * 256 + threadIdx.x; i < n; i += gridDim.x * 256) {
        int c = i / (TP2_ / 2), tc = i % (TP2_ / 2);
        int t = tc * 2;
        float v0 = 0.f, v1 = 0.f;
        if (c < CN_) {
            if (t < T_)     v0 = W2g[(size_t)c * T_ + t];
            if (t + 1 < T_) v1 = W2g[(size_t)c * T_ + t + 1];
        }
        u16 h0 = f2bf(v0), h1 = f2bf(v1);
        u16 l0 = f2bf(v0 - bf2f(h0)), l1 = f2bf(v1 - bf2f(h1));
        ((u32*)W2h)[i] = (u32)h0 | ((u32)h1 << 16);
        ((u32*)W2l)[i] = (u32)l0 | ((u32)l1 << 16);
    }
}

// ---------------------------------------------------------------------------
// K0e: W1 [x][h] -> W1th/W1tl [h][x] bf16 hi/lo (tiny).
// ---------------------------------------------------------------------------
__global__ __launch_bounds__(256) void k0_w1(const float* __restrict__ W1g,
                                             u16* __restrict__ W1th,
                                             u16* __restrict__ W1tl) {
    int i = blockIdx.x * 256 + threadIdx.x;
    if (i < HD_ * XD_) {
        int h = i / XD_, x = i % XD_;
        float v = W1g[(size_t)x * HD_ + h];
        u16 hi = f2bf(v);
        W1th[i] = hi;
        W1tl[i] = f2bf(v - bf2f(hi));
    }
}

// ---------------------------------------------------------------------------
// K12: unchanged (passed; gld_lds + counted vmcnt + dbuf).
// ---------------------------------------------------------------------------
__global__ __launch_bounds__(256, 1) void k12_mfma(const u16* __restrict__ W2h,
                                                   const u16* __restrict__ W2l,
                                                   const u16* __restrict__ Xth,
                                                   const u16* __restrict__ Xtl,
                                                   const u16* __restrict__ W1th,
                                                   const u16* __restrict__ W1tl,
                                                   u32* __restrict__ Ysi) {
    __shared__ __align__(16) u16 smem[49152];   // 96 KB = 2 bufs x 4 arrays x 96x64
    float* sZ = (float*)smem;                   // phase 2: 96 x 100 fp32 (38.4 KB, buf0 only)

    const int tid  = threadIdx.x;
    const int lane = tid & 63;
    const int w    = tid >> 6;            // 0..3: wave id == staging array id
    const int tx   = lane & 15;
    const int quad = lane >> 4;
    const int wr   = w >> 1;              // c-half (48 rows)
    const int wc2  = w & 1;               // x-half (48 cols)
    const int L    = blockIdx.x;
    const int xcd  = L & 7;
    const int slot = L >> 3;              // 0..31
    const int b    = xcd * 8 + (slot >> 2);
    const int c0   = (slot & 3) * 96;

    const u16* gsrc;
    size_t rowstart;
    if (w == 0)      { gsrc = W2h; rowstart = (size_t)c0; }
    else if (w == 1) { gsrc = W2l; rowstart = (size_t)c0; }
    else if (w == 2) { gsrc = Xth; rowstart = (size_t)b * XD_; }
    else             { gsrc = Xtl; rowstart = (size_t)b * XD_; }
    const int jg = (lane & 7) ^ ((lane >> 3) & 7);   // pre-swizzled source group

#define STAGE(bufsel, kk)                                                         \
    {                                                                             \
        u16* lb = smem + (bufsel) * 24576 + w * 6144;                             \
        _Pragma("unroll")                                                         \
        for (int i_ = 0; i_ < 12; i_++) {                                         \
            int row_ = i_ * 8 + (lane >> 3);                                      \
            const u16* gp_ = gsrc + (rowstart + row_) * TP2_ + (kk) + jg * 8;     \
            __builtin_amdgcn_global_load_lds(                                     \
                (const __attribute__((address_space(1))) u32*)(const void*)gp_,   \
                (__attribute__((address_space(3))) u32*)(void*)(lb + i_ * 512),   \
                16, 0, 0);                                                        \
        }                                                                         \
    }

    f32x4 accZ[3][3];
#pragma unroll
    for (int i = 0; i < 3; i++)
#pragma unroll
        for (int j = 0; j < 3; j++) accZ[i][j] = (f32x4){0.f, 0.f, 0.f, 0.f};

    STAGE(0, 0);
    for (int s = 0; s < 22; s++) {
        __builtin_amdgcn_sched_barrier(0);
        if (s < 21) {
            STAGE((s + 1) & 1, (s + 1) * 64);
            asm volatile("s_waitcnt vmcnt(12)" ::: "memory");  // cur tile landed
        } else {
            asm volatile("s_waitcnt vmcnt(0)" ::: "memory");
        }
        __builtin_amdgcn_s_barrier();
        __builtin_amdgcn_sched_barrier(0);
        const u16* bufp = smem + (s & 1) * 24576;
#pragma unroll
        for (int ks2 = 0; ks2 < 2; ks2++) {
            const int G = ks2 * 4 + quad;
            bf16x8 ah[3], al[3], bh3[3], bl3[3];
#pragma unroll
            for (int am = 0; am < 3; am++) {
                int row = wr * 48 + am * 16 + tx;
                int off = row * 64 + (G ^ (row & 7)) * 8;
                ah[am] = *(const bf16x8*)(bufp + off);
                al[am] = *(const bf16x8*)(bufp + 6144 + off);
            }
#pragma unroll
            for (int bn = 0; bn < 3; bn++) {
                int row = wc2 * 48 + bn * 16 + tx;
                int off = row * 64 + (G ^ (row & 7)) * 8;
                bh3[bn] = *(const bf16x8*)(bufp + 12288 + off);
                bl3[bn] = *(const bf16x8*)(bufp + 18432 + off);
            }
#pragma unroll
            for (int am = 0; am < 3; am++)
#pragma unroll
                for (int bn = 0; bn < 3; bn++) {
                    accZ[am][bn] = __builtin_amdgcn_mfma_f32_16x16x32_bf16(ah[am], bh3[bn], accZ[am][bn], 0, 0, 0);
                    accZ[am][bn] = __builtin_amdgcn_mfma_f32_16x16x32_bf16(ah[am], bl3[bn], accZ[am][bn], 0, 0, 0);
                    accZ[am][bn] = __builtin_amdgcn_mfma_f32_16x16x32_bf16(al[am], bh3[bn], accZ[am][bn], 0, 0, 0);
                }
        }
        asm volatile("s_waitcnt lgkmcnt(0)" ::: "memory");
        __builtin_amdgcn_sched_barrier(0);
        __builtin_amdgcn_s_barrier();
    }
#undef STAGE

    __builtin_amdgcn_sched_barrier(0);
#pragma unroll
    for (int am = 0; am < 3; am++)
#pragma unroll
        for (int bn = 0; bn < 3; bn++)
#pragma unroll
            for (int r = 0; r < 4; r++)
                sZ[(wr * 48 + am * 16 + quad * 4 + r) * 100 + wc2 * 48 + bn * 16 + tx] = accZ[am][bn][r];
    __syncthreads();

    bf16x8 A2h[3][3], A2l[3][3];
#pragma unroll
    for (int am = 0; am < 3; am++)
#pragma unroll
        for (int ks = 0; ks < 3; ks++) {
            const float* zrow = sZ + (wr * 48 + am * 16 + tx) * 100 + ks * 32 + quad * 8;
            bf16x8 vh, vl;
#pragma unroll
            for (int j = 0; j < 8; j++) {
                float v = zrow[j];
                u16 hi = f2bf(v);
                vh[j] = (short)hi;
                vl[j] = (short)f2bf(v - bf2f(hi));
            }
            A2h[am][ks] = vh; A2l[am][ks] = vl;
        }

    f32x4 accY[3][6];
#pragma unroll
    for (int i = 0; i < 3; i++)
#pragma unroll
        for (int j = 0; j < 6; j++) accY[i][j] = (f32x4){0.f, 0.f, 0.f, 0.f};
#pragma unroll
    for (int hn = 0; hn < 6; hn++) {
        const int hrow = wc2 * 96 + hn * 16 + tx;
#pragma unroll
        for (int ks = 0; ks < 3; ks++) {
            bf16x8 bh = *(const bf16x8*)(W1th + (size_t)hrow * XD_ + ks * 32 + quad * 8);
            bf16x8 bl = *(const bf16x8*)(W1tl + (size_t)hrow * XD_ + ks * 32 + quad * 8);
#pragma unroll
            for (int am = 0; am < 3; am++) {
                accY[am][hn] = __builtin_amdgcn_mfma_f32_16x16x32_bf16(A2h[am][ks], bh, accY[am][hn], 0, 0, 0);
                accY[am][hn] = __builtin_amdgcn_mfma_f32_16x16x32_bf16(A2h[am][ks], bl, accY[am][hn], 0, 0, 0);
                accY[am][hn] = __builtin_amdgcn_mfma_f32_16x16x32_bf16(A2l[am][ks], bh, accY[am][hn], 0, 0, 0);
            }
        }
    }

#pragma unroll
    for (int am = 0; am < 3; am++)
#pragma unroll
        for (int r = 0; r < 4; r++) {
            int c = c0 + wr * 48 + am * 16 + quad * 4 + r;
            if (c < CN_) {
                size_t base = ((size_t)b * CN_ + c) * HD_;
#pragma unroll
                for (int hn = 0; hn < 6; hn++) {
                    float y = SCALE_ * accY[am][hn][r];
                    u16 hi = f2bf(y);
                    u16 lo = f2bf(y - bf2f(hi));
                    Ysi[base + wc2 * 96 + hn * 16 + tx] = (u32)hi | ((u32)lo << 16);
                }
            }
        }
}

// ---------------------------------------------------------------------------
// K3: MFMA flash attention over a u-half.  THIS ROUND: 12-wave blocks.
// grid 256 = 1 block/CU exactly; block 768 = 12 waves handles TWO c-tiles
// (192 c-rows) of one (b,sp) pair, sharing one H staging (same bytes both
// tiles).  Evidence: rounds 4-7 stuck at Occupancy 16% (1 block of 6 waves
// per CU; 2x81,408 B LDS has zero slack at 160 KiB).  One 89,088 B block
// with 12 waves = 3 waves/SIMD guaranteed by construction.  Staging: 36
// gld_lds/iter = 3/wave, counted vmcnt(3).  All else is the round-7 code
// with the wave->row maps widened (w 0..11).
// ---------------------------------------------------------------------------
__global__ __launch_bounds__(768, 3) void k3_mfma(const u32* __restrict__ Ysi,
                                                  const u16* __restrict__ Hh,
                                                  const u16* __restrict__ Hl,
                                                  const u16* __restrict__ Hth,
                                                  float* __restrict__ Op,
                                                  float* __restrict__ Ml,
                                                  float* __restrict__ Ll) {
    __shared__ __align__(16) u16 smem[44544];   // 89,088 B: 73,728 H-dbuf + 15,360 sP

    const int tid  = threadIdx.x;
    const int lane = tid & 63;
    const int w    = tid >> 6;            // 0..11
    const int tx   = lane & 15;
    const int quad = lane >> 4;
    const int L    = blockIdx.x;
    const int xcd  = L & 7;
    const int slot = L >> 3;              // 0..31
    const int gp   = xcd * 16 + (slot >> 1);   // (b,sp) pair, 0..127
    const int ct   = slot & 1;                 // c-tile half (192 rows)
    const int b    = gp >> 1;
    const int sp   = gp & 1;
    const int c0   = ct * 192;
    const int us   = sp * TH_, ue = us + TH_;

    // ---- A-operand from interleaved Ysi (unpack once)
    bf16x8 Ah[6], Al[6];
    const int ar = c0 + w * 16 + tx;
    if (ar < CN_) {
        const u32* yi = Ysi + ((size_t)b * CN_ + ar) * HD_;
#pragma unroll
        for (int ks = 0; ks < 6; ks++) {
            u32 vv[8];
            *(uint4*)&vv[0] = *(const uint4*)(yi + ks * 32 + quad * 8);
            *(uint4*)&vv[4] = *(const uint4*)(yi + ks * 32 + quad * 8 + 4);
            bf16x8 hh, ll;
#pragma unroll
            for (int j = 0; j < 8; j++) {
                hh[j] = (short)(vv[j] & 0xffffu);
                ll[j] = (short)(vv[j] >> 16);
            }
            Ah[ks] = hh; Al[ks] = ll;
        }
    } else {
#pragma unroll
        for (int ks = 0; ks < 6; ks++) { Ah[ks] = (bf16x8)0; Al[ks] = (bf16x8)0; }
    }

    float m_s[4], l_s[4];
    f32x4 accO[12];
#pragma unroll
    for (int r = 0; r < 4; r++) { m_s[r] = -1e30f; l_s[r] = 0.f; }
#pragma unroll
    for (int j = 0; j < 12; j++) accO[j] = (f32x4){0.f, 0.f, 0.f, 0.f};

    // ---- per-lane staging descriptors: 36 gld_lds/iter, 3 per wave.
    // insts 0-11: sHh (tile 32u x 24 chunks); 12-23: sHl; 24-35: sHt
    // (192h x 4 chunks).  Source chunk pre-swizzled (involution with read).
    const char* srcp[3];
    u32 off0[3];
    const u32 incw = (u32)__builtin_amdgcn_readfirstlane((w < 8) ? (32 * HD_ * 2) : 64);
#pragma unroll
    for (int j = 0; j < 3; j++) {
        int k = w * 3 + j;
        u32 o;
        if (k < 24) {
            int arr = (k < 12) ? 0 : 1;
            int ii  = k - arr * 12;
            int cid = ii * 64 + lane;          // 0..767
            int u   = cid / 24, c1 = cid % 24;
            int c   = (c1 & ~7) | ((c1 & 7) ^ ((u >> 1) & 7));
            const u16* basep = (arr == 0 ? Hh : Hl) + (size_t)b * T_ * HD_;
            srcp[j] = (const char*)basep + ((size_t)(us + u) * HD_ + c * 8) * 2;
            o = (u32)(arr * 24576 + ii * 1024);
        } else {
            int ii  = k - 24;
            int cid = ii * 64 + lane;          // 0..767
            int h   = cid >> 2, c2 = cid & 3;
            int c   = c2 ^ ((h >> 2) & 3);
            const u16* basep = Hth + (size_t)b * HD_ * TP_;
            srcp[j] = (const char*)basep + ((size_t)h * TP_ + us + c * 8) * 2;
            o = (u32)(49152 + ii * 1024);
        }
        off0[j] = (u32)__builtin_amdgcn_readfirstlane((int)o);
    }

#define STAGE3(bufsel)                                                            \
    {                                                                             \
        _Pragma("unroll")                                                         \
        for (int j_ = 0; j_ < 3; j_++) {                                          \
            __builtin_amdgcn_global_load_lds(                                     \
                (const __attribute__((address_space(1))) u32*)(const void*)srcp[j_], \
                (__attribute__((address_space(3))) u32*)(void*)((char*)smem + off0[j_] + (bufsel) * 12288), \
                16, 0, 0);                                                        \
            srcp[j_] += incw;                                                     \
        }                                                                         \
    }

    u16* sPb = smem + 36864;                   // 192 x 40 u16 (byte 73,728)

    STAGE3(0);                                  // tile 0 -> buf 0
    for (int t = 0; t < 22; t++) {
        const int u0  = us + t * 32;
        const int buf = t & 1;
        __builtin_amdgcn_sched_barrier(0);
        if (t < 21) {
            STAGE3(buf ^ 1);                    // tile t+1 -> other buf
            asm volatile("s_waitcnt vmcnt(3)" ::: "memory");   // tile t landed
        } else {
            asm volatile("s_waitcnt vmcnt(0)" ::: "memory");
        }
        __builtin_amdgcn_s_barrier();
        __builtin_amdgcn_sched_barrier(0);

        const u16* Hhb = smem + buf * 6144;
        const u16* Hlb = smem + 12288 + buf * 6144;
        const u16* Htb = smem + 24576 + buf * 6144;

        // ---- GEMM1: S[c][u], K=192, split-bf16 (hi*hi + hi*lo + lo*hi)
        f32x4 s0a = {0.f, 0.f, 0.f, 0.f}, s1a = {0.f, 0.f, 0.f, 0.f};
        f32x4 s0b = {0.f, 0.f, 0.f, 0.f}, s1b = {0.f, 0.f, 0.f, 0.f};
        const int xr = (tx >> 1) & 7;           // same for row tx and 16+tx
        __builtin_amdgcn_s_setprio(1);
#pragma unroll
        for (int ks = 0; ks < 6; ks++) {
            const int cc = ks * 4 + quad;
            const int cs = (cc & ~7) | ((cc & 7) ^ xr);
            const int ro0 = tx * 192 + cs * 8;
            const int ro1 = (16 + tx) * 192 + cs * 8;
            bf16x8 bh0 = *(const bf16x8*)(Hhb + ro0);
            bf16x8 bl0 = *(const bf16x8*)(Hlb + ro0);
            bf16x8 bh1 = *(const bf16x8*)(Hhb + ro1);
            bf16x8 bl1 = *(const bf16x8*)(Hlb + ro1);
            s0a = __builtin_amdgcn_mfma_f32_16x16x32_bf16(Ah[ks], bh0, s0a, 0, 0, 0);
            s1a = __builtin_amdgcn_mfma_f32_16x16x32_bf16(Ah[ks], bl0, s1a, 0, 0, 0);
            s1a = __builtin_amdgcn_mfma_f32_16x16x32_bf16(Al[ks], bh0, s1a, 0, 0, 0);
            s0b = __builtin_amdgcn_mfma_f32_16x16x32_bf16(Ah[ks], bh1, s0b, 0, 0, 0);
            s1b = __builtin_amdgcn_mfma_f32_16x16x32_bf16(Ah[ks], bl1, s1b, 0, 0, 0);
            s1b = __builtin_amdgcn_mfma_f32_16x16x32_bf16(Al[ks], bh1, s1b, 0, 0, 0);
        }
        __builtin_amdgcn_s_setprio(0);
        float sv0[4], sv1[4];
        const bool okA = (u0 + tx) < ue, okB = (u0 + 16 + tx) < ue;
#pragma unroll
        for (int r = 0; r < 4; r++) {
            sv0[r] = okA ? (s0a[r] + s1a[r]) : -1e30f;
            sv1[r] = okB ? (s0b[r] + s1b[r]) : -1e30f;
        }

        // ---- online softmax; 16-lane reductions via DPP (VALU, no DS)
        float alpha[4];
#pragma unroll
        for (int r = 0; r < 4; r++) {
            float mx = red16_max(fmaxf(sv0[r], sv1[r]));
            float mn = fmaxf(m_s[r], mx);
            alpha[r] = __expf(m_s[r] - mn);
            float p0 = __expf(sv0[r] - mn);
            float p1 = __expf(sv1[r] - mn);
            sPb[(w * 16 + quad * 4 + r) * 40 + tx]      = f2bf(p0);
            sPb[(w * 16 + quad * 4 + r) * 40 + 16 + tx] = f2bf(p1);
            float s = red16_sum(p0 + p1);
            l_s[r] = l_s[r] * alpha[r] + s;
            m_s[r] = mn;
        }
        f32x4 alv = {alpha[0], alpha[1], alpha[2], alpha[3]};
#pragma unroll
        for (int j = 0; j < 12; j++) accO[j] *= alv;

        // ---- PV: O += P * H, K=32.  sP rows are wave-private (in-order DS).
        bf16x8 pa = *(const bf16x8*)(sPb + (w * 16 + tx) * 40 + quad * 8);
        const int ctq = quad ^ ((tx >> 2) & 3);
        __builtin_amdgcn_s_setprio(1);
#pragma unroll
        for (int j = 0; j < 12; j++) {
            bf16x8 hb = *(const bf16x8*)(Htb + (j * 16 + tx) * 32 + ctq * 8);
            accO[j] = __builtin_amdgcn_mfma_f32_16x16x32_bf16(pa, hb, accO[j], 0, 0, 0);
        }
        __builtin_amdgcn_s_setprio(0);

        // all LDS reads of buf done before any wave stages into it next iter
        asm volatile("s_waitcnt lgkmcnt(0)" ::: "memory");
        __builtin_amdgcn_sched_barrier(0);
        __builtin_amdgcn_s_barrier();
    }
#undef STAGE3

#pragma unroll
    for (int r = 0; r < 4; r++) {
        int c = c0 + w * 16 + quad * 4 + r;
        if (c < CN_) {
            float* orow = Op + (((size_t)sp * B_ + b) * CN_ + c) * HD_;
#pragma unroll
            for (int j = 0; j < 12; j++) orow[j * 16 + tx] = accO[j][r];
            if (tx == 0) {
                size_t mi = ((size_t)sp * B_ + b) * CN_ + c;
                Ml[mi] = m_s[r];
                Ll[mi] = l_s[r];
            }
        }
    }
}

// ---------------------------------------------------------------------------
// K4: merge the two u-half partials.
// ---------------------------------------------------------------------------
__global__ __launch_bounds__(192) void k_merge(const float* __restrict__ Op,
                                               const float* __restrict__ Ml,
                                               const float* __restrict__ Ll,
                                               float* __restrict__ out) {
    const int c = blockIdx.x, b = blockIdx.y, h = threadIdx.x;
    const size_t i0 = (size_t)b * CN_ + c;
    const size_t i1 = (size_t)B_ * CN_ + i0;
    float m0 = Ml[i0], m1 = Ml[i1];
    float l0 = Ll[i0], l1 = Ll[i1];
    float M  = fmaxf(m0, m1);
    float e0 = __expf(m0 - M), e1 = __expf(m1 - M);
    float L  = l0 * e0 + l1 * e1;
    float o0 = Op[i0 * HD_ + h], o1 = Op[i1 * HD_ + h];
    out[i0 * HD_ + h] = (o0 * e0 + o1 * e1) / L;
}

// ---------------------------------------------------------------------------
extern "C" void kernel_launch(void* const* d_in, const int* in_sizes, int n_in,
                              void* d_out, int out_size, void* d_ws, size_t ws_size,
                              hipStream_t stream) {
    const float* X  = (const float*)d_in[0];
    const float* H  = (const float*)d_in[1];
    const float* W1 = (const float*)d_in[2];
    const float* W2 = (const float*)d_in[3];
    float* out = (float*)d_out;

    char* ws = (char*)d_ws;
    u32*   Ysi  = (u32*)(ws);                    //  16,957,440 (interleaved hi|lo)
    u16*   Hh   = (u16*)(ws + 16957440);         //  33,914,880
    u16*   Hl   = (u16*)(ws + 50872320);         //  33,914,880
    u16*   Hth  = (u16*)(ws + 84787200);         //  34,209,792
    u16*   Xth  = (u16*)(ws + 118996992);        //  17,301,504  (aliased by Op later)
    u16*   Xtl  = (u16*)(ws + 136298496);        //  17,301,504
    float* Op   = (float*)(ws + 118996992);      //  33,914,880  (aliases Xth+Xtl; k12 done first)
    u16*   W2h  = (u16*)(ws + 153600000);        //   1,081,344
    u16*   W2l  = (u16*)(ws + 154681344);        //   1,081,344
    u16*   W1th = (u16*)(ws + 155762688);        //      36,864
    u16*   W1tl = (u16*)(ws + 155799552);        //      36,864
    float* Ml   = (float*)(ws + 155836416);      //     176,640
    float* Ll   = (float*)(ws + 156013056);      //     176,640  -> end 156,189,696

    k0_h    <<<dim3(22, 3, B_), 256, 0, stream>>>(H, Hh, Hl, Hth);
    k0_x    <<<dim3(22, B_),    256, 0, stream>>>(X, Xth, Xtl);
    k0_w2   <<<dim3(1056),      256, 0, stream>>>(W2, W2h, W2l);
    k0_w1   <<<dim3(72),        256, 0, stream>>>(W1, W1th, W1tl);
    k12_mfma<<<dim3(256),       256, 0, stream>>>(W2h, W2l, Xth, Xtl, W1th, W1tl, Ysi);
    k3_mfma <<<dim3(256),       768, 0, stream>>>(Ysi, Hh, Hl, Hth, Op, Ml, Ll);
    k_merge <<<dim3(CN_, B_),   192, 0, stream>>>(Op, Ml, Ll, out);
}